// Round 3
// baseline (9370.074 us; speedup 1.0000x reference)
//
#include <hip/hip_runtime.h>
#include <math.h>

#define H 6
#define D 128
#define K_ALL (H * D)   // 768

// ---------------- CSR build ----------------

__global__ __launch_bounds__(256) void hist_kernel(const int* __restrict__ dst,
                                                   int* __restrict__ deg, int E) {
    int e = blockIdx.x * blockDim.x + threadIdx.x;
    if (e < E) atomicAdd(&deg[dst[e]], 1);
}

__global__ __launch_bounds__(1024) void scan_kernel(const int* __restrict__ deg,
                                                    int* __restrict__ rowptr, int n) {
    __shared__ int wsum[16];
    __shared__ int carry;
    if (threadIdx.x == 0) carry = 0;
    __syncthreads();
    int lane = threadIdx.x & 63;
    int wv = (int)(threadIdx.x >> 6);
    for (int base = 0; base < n; base += 1024) {
        int i = base + (int)threadIdx.x;
        int v = (i < n) ? deg[i] : 0;
        int s = v;
        #pragma unroll
        for (int off = 1; off < 64; off <<= 1) {
            int t = __shfl_up(s, off, 64);
            if (lane >= off) s += t;
        }
        if (lane == 63) wsum[wv] = s;
        __syncthreads();
        if (threadIdx.x < 16) {
            int t = wsum[threadIdx.x];
            #pragma unroll
            for (int off = 1; off < 16; off <<= 1) {
                int u = __shfl_up(t, off, 64);
                if ((int)threadIdx.x >= off) t += u;
            }
            wsum[threadIdx.x] = t;
        }
        __syncthreads();
        int woff = (wv > 0) ? wsum[wv - 1] : 0;
        if (i < n) rowptr[i] = carry + woff + s - v;
        __syncthreads();
        if (threadIdx.x == 0) carry += wsum[15];
        __syncthreads();
    }
}

__global__ __launch_bounds__(256) void scatter_kernel(const int* __restrict__ src,
                                                      const int* __restrict__ dst,
                                                      int* __restrict__ rowcur,
                                                      int* __restrict__ col, int E) {
    int e = blockIdx.x * blockDim.x + threadIdx.x;
    if (e < E) {
        int p = atomicAdd(&rowcur[dst[e]], 1);
        col[p] = src[e];
    }
}

// ---------------- per-layer kernels ----------------

__global__ __launch_bounds__(256) void fold_att_kernel(const float* __restrict__ W,
                                                       const float* __restrict__ att_src,
                                                       const float* __restrict__ att_dst,
                                                       float* __restrict__ wa) {
    int t = blockIdx.x * blockDim.x + threadIdx.x;
    if (t >= 128 * 12) return;
    int k = t / 12, j = t % 12;
    int h = (j < 6) ? j : (j - 6);
    const float* att = (j < 6) ? att_src : att_dst;
    const float* wrow = W + (size_t)k * K_ALL + h * D;
    const float* arow = att + h * D;
    float s = 0.f;
    #pragma unroll 8
    for (int c = 0; c < D; c++) s += wrow[c] * arow[c];
    wa[k * 12 + j] = s;
}

__global__ __launch_bounds__(256) void compute_a_kernel(const float* __restrict__ x,
                                                        const float* __restrict__ wa,
                                                        float* __restrict__ a, int n_nodes) {
    __shared__ float swa[128 * 12];
    for (int i = threadIdx.x; i < 128 * 12; i += 256) swa[i] = wa[i];
    __syncthreads();
    int wid = (int)((blockIdx.x * blockDim.x + threadIdx.x) >> 6);
    int lane = threadIdx.x & 63;
    if (wid >= n_nodes) return;
    float x0 = x[(size_t)wid * D + lane];
    float x1 = x[(size_t)wid * D + 64 + lane];
    #pragma unroll
    for (int j = 0; j < 12; j++) {
        float p = x0 * swa[lane * 12 + j] + x1 * swa[(64 + lane) * 12 + j];
        #pragma unroll
        for (int off = 32; off; off >>= 1) p += __shfl_xor(p, off, 64);
        if (lane == 0) a[(size_t)wid * 12 + j] = p;
    }
}

__device__ __forceinline__ float rlf(float v, int j) {
    return __int_as_float(__builtin_amdgcn_readlane(__float_as_int(v), j));
}

// One wave per dst node; lane-parallel softmax; readlane-broadcast, 2-deep
// software-pipelined x-gather; channels c = 2*lane, 2*lane+1 (float2).
__global__ __launch_bounds__(256) void aggregate_kernel(const float* __restrict__ x,
                                                        const float* __restrict__ a,
                                                        const int* __restrict__ rowend,
                                                        const int* __restrict__ deg_,
                                                        const int* __restrict__ col,
                                                        float* __restrict__ agg, int n_nodes) {
    int wid = (int)((blockIdx.x * blockDim.x + threadIdx.x) >> 6);
    int lane = threadIdx.x & 63;
    if (wid >= n_nodes) return;
    const int n = wid;
    const int deg = deg_[n];
    const int start = rowend[n] - deg;
    const int nent = deg + 1;

    float adst[H];
    #pragma unroll
    for (int h = 0; h < H; h++) adst[h] = a[(size_t)n * 12 + 6 + h];

    float* og = agg + (size_t)n * (H * D);

    if (nent <= 64) {
        const bool act = lane < nent;
        int s = n;                          // lane 'deg' = self loop
        if (lane < deg) s = col[start + lane];

        const float* as_ = a + (size_t)s * 12;
        float4 v0 = *(const float4*)as_;
        float2 v1 = *(const float2*)(as_ + 4);
        float e0 = v0.x + adst[0], e1 = v0.y + adst[1], e2 = v0.z + adst[2];
        float e3 = v0.w + adst[3], e4 = v1.x + adst[4], e5 = v1.y + adst[5];
        e0 = e0 > 0.f ? e0 : 0.2f * e0;  e1 = e1 > 0.f ? e1 : 0.2f * e1;
        e2 = e2 > 0.f ? e2 : 0.2f * e2;  e3 = e3 > 0.f ? e3 : 0.2f * e3;
        e4 = e4 > 0.f ? e4 : 0.2f * e4;  e5 = e5 > 0.f ? e5 : 0.2f * e5;
        if (!act) { e0 = e1 = e2 = e3 = e4 = e5 = -1e30f; }

        float m0 = e0, m1 = e1, m2 = e2, m3 = e3, m4 = e4, m5 = e5;
        #pragma unroll
        for (int off = 32; off; off >>= 1) {
            m0 = fmaxf(m0, __shfl_xor(m0, off, 64));
            m1 = fmaxf(m1, __shfl_xor(m1, off, 64));
            m2 = fmaxf(m2, __shfl_xor(m2, off, 64));
            m3 = fmaxf(m3, __shfl_xor(m3, off, 64));
            m4 = fmaxf(m4, __shfl_xor(m4, off, 64));
            m5 = fmaxf(m5, __shfl_xor(m5, off, 64));
        }
        float w0 = act ? __expf(e0 - m0) : 0.f;
        float w1 = act ? __expf(e1 - m1) : 0.f;
        float w2 = act ? __expf(e2 - m2) : 0.f;
        float w3 = act ? __expf(e3 - m3) : 0.f;
        float w4 = act ? __expf(e4 - m4) : 0.f;
        float w5 = act ? __expf(e5 - m5) : 0.f;
        float d0 = w0, d1 = w1, d2 = w2, d3 = w3, d4 = w4, d5 = w5;
        #pragma unroll
        for (int off = 32; off; off >>= 1) {
            d0 += __shfl_xor(d0, off, 64);  d1 += __shfl_xor(d1, off, 64);
            d2 += __shfl_xor(d2, off, 64);  d3 += __shfl_xor(d3, off, 64);
            d4 += __shfl_xor(d4, off, 64);  d5 += __shfl_xor(d5, off, 64);
        }
        w0 *= 1.f / (d0 + 1e-16f);  w1 *= 1.f / (d1 + 1e-16f);
        w2 *= 1.f / (d2 + 1e-16f);  w3 *= 1.f / (d3 + 1e-16f);
        w4 *= 1.f / (d4 + 1e-16f);  w5 *= 1.f / (d5 + 1e-16f);

        float a00 = 0, a01 = 0, a02 = 0, a03 = 0, a04 = 0, a05 = 0;
        float a10 = 0, a11 = 0, a12 = 0, a13 = 0, a14 = 0, a15 = 0;
        const float* xb = x + (lane << 1);

        // 2-deep software-pipelined gather, readlane broadcasts (SALU, no DS)
        float2 xa, xbv;
        {
            int s0 = __builtin_amdgcn_readlane(s, 0);
            xa = *(const float2*)(xb + (size_t)s0 * D);
        }
        xbv = make_float2(0.f, 0.f);
        if (nent > 1) {
            int s1 = __builtin_amdgcn_readlane(s, 1);
            xbv = *(const float2*)(xb + (size_t)s1 * D);
        }
        for (int j = 0; j < nent; j += 2) {
            float2 xn0 = make_float2(0.f, 0.f), xn1 = make_float2(0.f, 0.f);
            if (j + 2 < nent) {
                int s2 = __builtin_amdgcn_readlane(s, j + 2);
                xn0 = *(const float2*)(xb + (size_t)s2 * D);
            }
            if (j + 3 < nent) {
                int s3 = __builtin_amdgcn_readlane(s, j + 3);
                xn1 = *(const float2*)(xb + (size_t)s3 * D);
            }
            {
                float b0 = rlf(w0, j), b1 = rlf(w1, j), b2 = rlf(w2, j);
                float b3 = rlf(w3, j), b4 = rlf(w4, j), b5 = rlf(w5, j);
                a00 += b0 * xa.x; a10 += b0 * xa.y;
                a01 += b1 * xa.x; a11 += b1 * xa.y;
                a02 += b2 * xa.x; a12 += b2 * xa.y;
                a03 += b3 * xa.x; a13 += b3 * xa.y;
                a04 += b4 * xa.x; a14 += b4 * xa.y;
                a05 += b5 * xa.x; a15 += b5 * xa.y;
            }
            if (j + 1 < nent) {
                float b0 = rlf(w0, j + 1), b1 = rlf(w1, j + 1), b2 = rlf(w2, j + 1);
                float b3 = rlf(w3, j + 1), b4 = rlf(w4, j + 1), b5 = rlf(w5, j + 1);
                a00 += b0 * xbv.x; a10 += b0 * xbv.y;
                a01 += b1 * xbv.x; a11 += b1 * xbv.y;
                a02 += b2 * xbv.x; a12 += b2 * xbv.y;
                a03 += b3 * xbv.x; a13 += b3 * xbv.y;
                a04 += b4 * xbv.x; a14 += b4 * xbv.y;
                a05 += b5 * xbv.x; a15 += b5 * xbv.y;
            }
            xa = xn0; xbv = xn1;
        }
        int c = lane << 1;
        *(float2*)(og + 0 * D + c) = make_float2(a00, a10);
        *(float2*)(og + 1 * D + c) = make_float2(a01, a11);
        *(float2*)(og + 2 * D + c) = make_float2(a02, a12);
        *(float2*)(og + 3 * D + c) = make_float2(a03, a13);
        *(float2*)(og + 4 * D + c) = make_float2(a04, a14);
        *(float2*)(og + 5 * D + c) = make_float2(a05, a15);
    } else {
        // slow fallback (deg >= 64)
        float m[H];
        #pragma unroll
        for (int h = 0; h < H; h++) {
            float e = a[(size_t)n * 12 + h] + adst[h];
            m[h] = (e > 0.f) ? e : 0.2f * e;
        }
        for (int j = 0; j < deg; j++) {
            int s = col[start + j];
            #pragma unroll
            for (int h = 0; h < H; h++) {
                float e = a[(size_t)s * 12 + h] + adst[h];
                e = (e > 0.f) ? e : 0.2f * e;
                m[h] = fmaxf(m[h], e);
            }
        }
        float d[H] = {0, 0, 0, 0, 0, 0};
        float acc0[H] = {0, 0, 0, 0, 0, 0};
        float acc1[H] = {0, 0, 0, 0, 0, 0};
        int c0 = lane, c1 = 64 + lane;
        for (int j = 0; j <= deg; j++) {
            int s = (j < deg) ? col[start + j] : n;
            float w[H];
            #pragma unroll
            for (int h = 0; h < H; h++) {
                float e = a[(size_t)s * 12 + h] + adst[h];
                e = (e > 0.f) ? e : 0.2f * e;
                w[h] = __expf(e - m[h]);
                d[h] += w[h];
            }
            float xv0 = x[(size_t)s * D + c0];
            float xv1 = x[(size_t)s * D + c1];
            #pragma unroll
            for (int h = 0; h < H; h++) {
                acc0[h] += w[h] * xv0;
                acc1[h] += w[h] * xv1;
            }
        }
        #pragma unroll
        for (int h = 0; h < H; h++) {
            float inv = 1.0f / (d[h] + 1e-16f);
            og[h * D + c0] = acc0[h] * inv;
            og[h * D + c1] = acc1[h] * inv;
        }
    }
}

// ---------------- GEMM: part[ky][m][c] = sum_{k in chunk ky} agg[m][k]*B[k][c] ----------------
// B[k][c] = W[k&127][(k>>7)*128 + c]
#define BM 64
#define BN 128
#define BK 32
#define SPLITK 3
#define KCHUNK (K_ALL / SPLITK)   // 256

__global__ __launch_bounds__(512) void gemm_part_kernel(const float* __restrict__ A,
                                                        const float* __restrict__ W,
                                                        float* __restrict__ part, int M) {
    __shared__ float As[BK][BM + 4];   // transposed; row stride 68 floats (16B-aligned)
    __shared__ float Bs[BK][BN];
    const int m0 = blockIdx.x * BM;
    const int k_begin = blockIdx.y * KCHUNK;
    const int tid = threadIdx.x;
    const int tm = tid >> 5;          // 0..15 -> rows tm*4..tm*4+3
    const int tn = tid & 31;          // 0..31 -> cols tn*4..tn*4+3

    const int ar = tid >> 3;          // 0..63 (A stage row)
    const int ac = (tid & 7) * 4;     // 0..28 (A stage k-offset)

    float acc[4][4] = {{0.f}};

    float4 aReg;
    float4 bReg[2];
    // prefetch tile 0
    {
        int m = m0 + ar;
        aReg = make_float4(0.f, 0.f, 0.f, 0.f);
        if (m < M) aReg = *(const float4*)(A + (size_t)m * K_ALL + k_begin + ac);
        int h128 = (k_begin >> 7) << 7;
        int kb = k_begin & 127;
        #pragma unroll
        for (int i = 0; i < 2; i++) {
            int j = i * 512 + tid;
            int r = j >> 5, cc = (j & 31) * 4;
            bReg[i] = *(const float4*)(W + (size_t)(kb + r) * K_ALL + h128 + cc);
        }
    }

    #pragma unroll
    for (int t = 0; t < KCHUNK / BK; t++) {
        As[ac + 0][ar] = aReg.x;
        As[ac + 1][ar] = aReg.y;
        As[ac + 2][ar] = aReg.z;
        As[ac + 3][ar] = aReg.w;
        #pragma unroll
        for (int i = 0; i < 2; i++) {
            int j = i * 512 + tid;
            int r = j >> 5, cc = (j & 31) * 4;
            *(float4*)&Bs[r][cc] = bReg[i];
        }
        __syncthreads();

        if (t + 1 < KCHUNK / BK) {
            int k0 = k_begin + (t + 1) * BK;
            int m = m0 + ar;
            aReg = make_float4(0.f, 0.f, 0.f, 0.f);
            if (m < M) aReg = *(const float4*)(A + (size_t)m * K_ALL + k0 + ac);
            int h128 = (k0 >> 7) << 7;
            int kb = k0 & 127;
            #pragma unroll
            for (int i = 0; i < 2; i++) {
                int j = i * 512 + tid;
                int r = j >> 5, cc = (j & 31) * 4;
                bReg[i] = *(const float4*)(W + (size_t)(kb + r) * K_ALL + h128 + cc);
            }
        }

        #pragma unroll
        for (int kk = 0; kk < BK; kk++) {
            float4 a4 = *(const float4*)&As[kk][tm * 4];
            float4 b4 = *(const float4*)&Bs[kk][tn * 4];
            acc[0][0] += a4.x * b4.x; acc[0][1] += a4.x * b4.y;
            acc[0][2] += a4.x * b4.z; acc[0][3] += a4.x * b4.w;
            acc[1][0] += a4.y * b4.x; acc[1][1] += a4.y * b4.y;
            acc[1][2] += a4.y * b4.z; acc[1][3] += a4.y * b4.w;
            acc[2][0] += a4.z * b4.x; acc[2][1] += a4.z * b4.y;
            acc[2][2] += a4.z * b4.z; acc[2][3] += a4.z * b4.w;
            acc[3][0] += a4.w * b4.x; acc[3][1] += a4.w * b4.y;
            acc[3][2] += a4.w * b4.z; acc[3][3] += a4.w * b4.w;
        }
        __syncthreads();
    }

    float* pp = part + (size_t)blockIdx.y * M * D;
    #pragma unroll
    for (int i = 0; i < 4; i++) {
        int m = m0 + tm * 4 + i;
        if (m < M) {
            float4 v = make_float4(acc[i][0], acc[i][1], acc[i][2], acc[i][3]);
            *(float4*)(pp + (size_t)m * D + tn * 4) = v;
        }
    }
}

// out = relu((p0+p1+p2)/6 + bias)
__global__ __launch_bounds__(256) void reduce_kernel(const float* __restrict__ part,
                                                     const float* __restrict__ bias,
                                                     float* __restrict__ out, int M) {
    int idx = blockIdx.x * blockDim.x + threadIdx.x;   // float4 index
    int total = M * (D / 4);
    if (idx >= total) return;
    const float4* p0 = (const float4*)part;
    const float4* p1 = p0 + (size_t)M * (D / 4);
    const float4* p2 = p1 + (size_t)M * (D / 4);
    float4 v0 = p0[idx], v1 = p1[idx], v2 = p2[idx];
    float4 bv = *(const float4*)(bias + (idx & (D / 4 - 1)) * 4);
    const float inv6 = 1.0f / 6.0f;
    float4 r;
    r.x = (v0.x + v1.x + v2.x) * inv6 + bv.x;
    r.y = (v0.y + v1.y + v2.y) * inv6 + bv.y;
    r.z = (v0.z + v1.z + v2.z) * inv6 + bv.z;
    r.w = (v0.w + v1.w + v2.w) * inv6 + bv.w;
    r.x = r.x > 0.f ? r.x : 0.f;
    r.y = r.y > 0.f ? r.y : 0.f;
    r.z = r.z > 0.f ? r.z : 0.f;
    r.w = r.w > 0.f ? r.w : 0.f;
    ((float4*)out)[idx] = r;
}

// ---------------- host ----------------

extern "C" void kernel_launch(void* const* d_in, const int* in_sizes, int n_in,
                              void* d_out, int out_size, void* d_ws, size_t ws_size,
                              hipStream_t stream) {
    const float* x_in = (const float*)d_in[0];
    const int* ei = (const int*)d_in[1];
    int N = in_sizes[0] / D;
    int E = in_sizes[1] / 2;
    const int* srcp = ei;
    const int* dstp = ei + E;

    float* ws = (float*)d_ws;
    float* bufA = ws;
    float* bufB = bufA + (size_t)N * D;
    float* abuf = bufB + (size_t)N * D;
    float* wa = abuf + (size_t)N * 12;
    float* agg = wa + 128 * 12;
    float* part = agg + (size_t)N * (H * D);
    int* rowptr = (int*)(part + (size_t)SPLITK * N * D);
    int* deg = rowptr + (N + 1);
    int* col = deg + N;

    // CSR build
    hipMemsetAsync(deg, 0, (size_t)N * sizeof(int), stream);
    hist_kernel<<<(E + 255) / 256, 256, 0, stream>>>(dstp, deg, E);
    scan_kernel<<<1, 1024, 0, stream>>>(deg, rowptr, N);
    scatter_kernel<<<(E + 255) / 256, 256, 0, stream>>>(srcp, dstp, rowptr, col, E);

    const float* xcur = x_in;
    for (int l = 0; l < 4; l++) {
        const float* W   = (const float*)d_in[2 + 4 * l];
        const float* as_ = (const float*)d_in[3 + 4 * l];
        const float* ad_ = (const float*)d_in[4 + 4 * l];
        const float* b   = (const float*)d_in[5 + 4 * l];
        float* xout = (l == 3) ? (float*)d_out : ((l & 1) ? bufB : bufA);

        fold_att_kernel<<<6, 256, 0, stream>>>(W, as_, ad_, wa);
        compute_a_kernel<<<(N + 3) / 4, 256, 0, stream>>>(xcur, wa, abuf, N);
        aggregate_kernel<<<(N + 3) / 4, 256, 0, stream>>>(xcur, abuf, rowptr, deg, col, agg, N);
        gemm_part_kernel<<<dim3((N + BM - 1) / BM, SPLITK), 512, 0, stream>>>(agg, W, part, N);
        reduce_kernel<<<(N * (D / 4) + 255) / 256, 256, 0, stream>>>(part, b, xout, N);

        xcur = xout;
    }
}

// Round 4
// 391.889 us; speedup vs baseline: 23.9100x; 23.9100x over previous
//
#include <hip/hip_runtime.h>
#include <math.h>

#define H 6
#define D 128
#define K_ALL (H * D)   // 768

// ---------------- CSR build ----------------

__global__ __launch_bounds__(256) void hist_kernel(const int* __restrict__ dst,
                                                   int* __restrict__ deg, int E) {
    int e = blockIdx.x * blockDim.x + threadIdx.x;
    if (e < E) atomicAdd(&deg[dst[e]], 1);
}

__global__ __launch_bounds__(1024) void scan_kernel(const int* __restrict__ deg,
                                                    int* __restrict__ rowptr, int n) {
    __shared__ int wsum[16];
    __shared__ int carry;
    if (threadIdx.x == 0) carry = 0;
    __syncthreads();
    int lane = threadIdx.x & 63;
    int wv = (int)(threadIdx.x >> 6);
    for (int base = 0; base < n; base += 1024) {
        int i = base + (int)threadIdx.x;
        int v = (i < n) ? deg[i] : 0;
        int s = v;
        #pragma unroll
        for (int off = 1; off < 64; off <<= 1) {
            int t = __shfl_up(s, off, 64);
            if (lane >= off) s += t;
        }
        if (lane == 63) wsum[wv] = s;
        __syncthreads();
        if (threadIdx.x < 16) {
            int t = wsum[threadIdx.x];
            #pragma unroll
            for (int off = 1; off < 16; off <<= 1) {
                int u = __shfl_up(t, off, 64);
                if ((int)threadIdx.x >= off) t += u;
            }
            wsum[threadIdx.x] = t;
        }
        __syncthreads();
        int woff = (wv > 0) ? wsum[wv - 1] : 0;
        if (i < n) rowptr[i] = carry + woff + s - v;
        __syncthreads();
        if (threadIdx.x == 0) carry += wsum[15];
        __syncthreads();
    }
}

__global__ __launch_bounds__(256) void scatter_kernel(const int* __restrict__ src,
                                                      const int* __restrict__ dst,
                                                      int* __restrict__ rowcur,
                                                      int* __restrict__ col, int E) {
    int e = blockIdx.x * blockDim.x + threadIdx.x;
    if (e < E) {
        int p = atomicAdd(&rowcur[dst[e]], 1);
        col[p] = src[e];
    }
}

// ---------------- per-layer kernels ----------------

__global__ __launch_bounds__(256) void fold_att_kernel(const float* __restrict__ W,
                                                       const float* __restrict__ att_src,
                                                       const float* __restrict__ att_dst,
                                                       float* __restrict__ wa) {
    int t = blockIdx.x * blockDim.x + threadIdx.x;
    if (t >= 128 * 12) return;
    int k = t / 12, j = t % 12;
    int h = (j < 6) ? j : (j - 6);
    const float* att = (j < 6) ? att_src : att_dst;
    const float* wrow = W + (size_t)k * K_ALL + h * D;
    const float* arow = att + h * D;
    float s = 0.f;
    #pragma unroll 8
    for (int c = 0; c < D; c++) s += wrow[c] * arow[c];
    wa[k * 12 + j] = s;
}

__global__ __launch_bounds__(256) void compute_a_kernel(const float* __restrict__ x,
                                                        const float* __restrict__ wa,
                                                        float* __restrict__ a, int n_nodes) {
    __shared__ float swa[128 * 12];
    for (int i = threadIdx.x; i < 128 * 12; i += 256) swa[i] = wa[i];
    __syncthreads();
    int wid = (int)((blockIdx.x * blockDim.x + threadIdx.x) >> 6);
    int lane = threadIdx.x & 63;
    if (wid >= n_nodes) return;
    float x0 = x[(size_t)wid * D + lane];
    float x1 = x[(size_t)wid * D + 64 + lane];
    #pragma unroll
    for (int j = 0; j < 12; j++) {
        float p = x0 * swa[lane * 12 + j] + x1 * swa[(64 + lane) * 12 + j];
        #pragma unroll
        for (int off = 32; off; off >>= 1) p += __shfl_xor(p, off, 64);
        if (lane == 0) a[(size_t)wid * 12 + j] = p;
    }
}

__device__ __forceinline__ float rlf(float v, int j) {
    return __int_as_float(__builtin_amdgcn_readlane(__float_as_int(v), j));
}

// One wave per dst node; lane-parallel softmax; readlane-broadcast, 2-deep
// software-pipelined x-gather; channels c = 2*lane, 2*lane+1 (float2).
__global__ __launch_bounds__(256) void aggregate_kernel(const float* __restrict__ x,
                                                        const float* __restrict__ a,
                                                        const int* __restrict__ rowend,
                                                        const int* __restrict__ deg_,
                                                        const int* __restrict__ col,
                                                        float* __restrict__ agg, int n_nodes) {
    int wid = (int)((blockIdx.x * blockDim.x + threadIdx.x) >> 6);
    int lane = threadIdx.x & 63;
    if (wid >= n_nodes) return;
    const int n = wid;
    const int deg = deg_[n];
    const int start = rowend[n] - deg;
    const int nent = deg + 1;

    float adst[H];
    #pragma unroll
    for (int h = 0; h < H; h++) adst[h] = a[(size_t)n * 12 + 6 + h];

    float* og = agg + (size_t)n * (H * D);

    if (nent <= 64) {
        const bool act = lane < nent;
        int s = n;                          // lane 'deg' = self loop
        if (lane < deg) s = col[start + lane];

        const float* as_ = a + (size_t)s * 12;
        float4 v0 = *(const float4*)as_;
        float2 v1 = *(const float2*)(as_ + 4);
        float e0 = v0.x + adst[0], e1 = v0.y + adst[1], e2 = v0.z + adst[2];
        float e3 = v0.w + adst[3], e4 = v1.x + adst[4], e5 = v1.y + adst[5];
        e0 = e0 > 0.f ? e0 : 0.2f * e0;  e1 = e1 > 0.f ? e1 : 0.2f * e1;
        e2 = e2 > 0.f ? e2 : 0.2f * e2;  e3 = e3 > 0.f ? e3 : 0.2f * e3;
        e4 = e4 > 0.f ? e4 : 0.2f * e4;  e5 = e5 > 0.f ? e5 : 0.2f * e5;
        if (!act) { e0 = e1 = e2 = e3 = e4 = e5 = -1e30f; }

        float m0 = e0, m1 = e1, m2 = e2, m3 = e3, m4 = e4, m5 = e5;
        #pragma unroll
        for (int off = 32; off; off >>= 1) {
            m0 = fmaxf(m0, __shfl_xor(m0, off, 64));
            m1 = fmaxf(m1, __shfl_xor(m1, off, 64));
            m2 = fmaxf(m2, __shfl_xor(m2, off, 64));
            m3 = fmaxf(m3, __shfl_xor(m3, off, 64));
            m4 = fmaxf(m4, __shfl_xor(m4, off, 64));
            m5 = fmaxf(m5, __shfl_xor(m5, off, 64));
        }
        float w0 = act ? __expf(e0 - m0) : 0.f;
        float w1 = act ? __expf(e1 - m1) : 0.f;
        float w2 = act ? __expf(e2 - m2) : 0.f;
        float w3 = act ? __expf(e3 - m3) : 0.f;
        float w4 = act ? __expf(e4 - m4) : 0.f;
        float w5 = act ? __expf(e5 - m5) : 0.f;
        float d0 = w0, d1 = w1, d2 = w2, d3 = w3, d4 = w4, d5 = w5;
        #pragma unroll
        for (int off = 32; off; off >>= 1) {
            d0 += __shfl_xor(d0, off, 64);  d1 += __shfl_xor(d1, off, 64);
            d2 += __shfl_xor(d2, off, 64);  d3 += __shfl_xor(d3, off, 64);
            d4 += __shfl_xor(d4, off, 64);  d5 += __shfl_xor(d5, off, 64);
        }
        w0 *= 1.f / (d0 + 1e-16f);  w1 *= 1.f / (d1 + 1e-16f);
        w2 *= 1.f / (d2 + 1e-16f);  w3 *= 1.f / (d3 + 1e-16f);
        w4 *= 1.f / (d4 + 1e-16f);  w5 *= 1.f / (d5 + 1e-16f);

        float a00 = 0, a01 = 0, a02 = 0, a03 = 0, a04 = 0, a05 = 0;
        float a10 = 0, a11 = 0, a12 = 0, a13 = 0, a14 = 0, a15 = 0;
        const float* xb = x + (lane << 1);

        float2 xa, xbv;
        {
            int s0 = __builtin_amdgcn_readlane(s, 0);
            xa = *(const float2*)(xb + (size_t)s0 * D);
        }
        xbv = make_float2(0.f, 0.f);
        if (nent > 1) {
            int s1 = __builtin_amdgcn_readlane(s, 1);
            xbv = *(const float2*)(xb + (size_t)s1 * D);
        }
        for (int j = 0; j < nent; j += 2) {
            float2 xn0 = make_float2(0.f, 0.f), xn1 = make_float2(0.f, 0.f);
            if (j + 2 < nent) {
                int s2 = __builtin_amdgcn_readlane(s, j + 2);
                xn0 = *(const float2*)(xb + (size_t)s2 * D);
            }
            if (j + 3 < nent) {
                int s3 = __builtin_amdgcn_readlane(s, j + 3);
                xn1 = *(const float2*)(xb + (size_t)s3 * D);
            }
            {
                float b0 = rlf(w0, j), b1 = rlf(w1, j), b2 = rlf(w2, j);
                float b3 = rlf(w3, j), b4 = rlf(w4, j), b5 = rlf(w5, j);
                a00 += b0 * xa.x; a10 += b0 * xa.y;
                a01 += b1 * xa.x; a11 += b1 * xa.y;
                a02 += b2 * xa.x; a12 += b2 * xa.y;
                a03 += b3 * xa.x; a13 += b3 * xa.y;
                a04 += b4 * xa.x; a14 += b4 * xa.y;
                a05 += b5 * xa.x; a15 += b5 * xa.y;
            }
            if (j + 1 < nent) {
                float b0 = rlf(w0, j + 1), b1 = rlf(w1, j + 1), b2 = rlf(w2, j + 1);
                float b3 = rlf(w3, j + 1), b4 = rlf(w4, j + 1), b5 = rlf(w5, j + 1);
                a00 += b0 * xbv.x; a10 += b0 * xbv.y;
                a01 += b1 * xbv.x; a11 += b1 * xbv.y;
                a02 += b2 * xbv.x; a12 += b2 * xbv.y;
                a03 += b3 * xbv.x; a13 += b3 * xbv.y;
                a04 += b4 * xbv.x; a14 += b4 * xbv.y;
                a05 += b5 * xbv.x; a15 += b5 * xbv.y;
            }
            xa = xn0; xbv = xn1;
        }
        int c = lane << 1;
        *(float2*)(og + 0 * D + c) = make_float2(a00, a10);
        *(float2*)(og + 1 * D + c) = make_float2(a01, a11);
        *(float2*)(og + 2 * D + c) = make_float2(a02, a12);
        *(float2*)(og + 3 * D + c) = make_float2(a03, a13);
        *(float2*)(og + 4 * D + c) = make_float2(a04, a14);
        *(float2*)(og + 5 * D + c) = make_float2(a05, a15);
    } else {
        // slow fallback (deg >= 64)
        float m[H];
        #pragma unroll
        for (int h = 0; h < H; h++) {
            float e = a[(size_t)n * 12 + h] + adst[h];
            m[h] = (e > 0.f) ? e : 0.2f * e;
        }
        for (int j = 0; j < deg; j++) {
            int s = col[start + j];
            #pragma unroll
            for (int h = 0; h < H; h++) {
                float e = a[(size_t)s * 12 + h] + adst[h];
                e = (e > 0.f) ? e : 0.2f * e;
                m[h] = fmaxf(m[h], e);
            }
        }
        float d[H] = {0, 0, 0, 0, 0, 0};
        float acc0[H] = {0, 0, 0, 0, 0, 0};
        float acc1[H] = {0, 0, 0, 0, 0, 0};
        int c0 = lane, c1 = 64 + lane;
        for (int j = 0; j <= deg; j++) {
            int s = (j < deg) ? col[start + j] : n;
            float w[H];
            #pragma unroll
            for (int h = 0; h < H; h++) {
                float e = a[(size_t)s * 12 + h] + adst[h];
                e = (e > 0.f) ? e : 0.2f * e;
                w[h] = __expf(e - m[h]);
                d[h] += w[h];
            }
            float xv0 = x[(size_t)s * D + c0];
            float xv1 = x[(size_t)s * D + c1];
            #pragma unroll
            for (int h = 0; h < H; h++) {
                acc0[h] += w[h] * xv0;
                acc1[h] += w[h] * xv1;
            }
        }
        #pragma unroll
        for (int h = 0; h < H; h++) {
            float inv = 1.0f / (d[h] + 1e-16f);
            og[h * D + c0] = acc0[h] * inv;
            og[h * D + c1] = acc1[h] * inv;
        }
    }
}

// ---------------- GEMM: part[ky][m][c] = sum_{k in chunk ky} agg[m][k]*B[k][c] ----------------
// B[k][c] = W[k&127][(k>>7)*128 + c]
// Round-2-proven structure: single-buffered, no outer unroll, no manual
// register prefetch (round-3's spill lesson). 4x8 micro-tile, 256 threads.
#define BM 64
#define BN 128
#define BK 32
#define SPLITK 3
#define KCHUNK (K_ALL / SPLITK)   // 256

__global__ __launch_bounds__(256) void gemm_part_kernel(const float* __restrict__ A,
                                                        const float* __restrict__ W,
                                                        float* __restrict__ part, int M) {
    __shared__ float As[BK][BM + 4];   // transposed A; row stride 68 floats
    __shared__ float Bs[BK][BN];
    const int m0 = blockIdx.x * BM;
    const int k_begin = blockIdx.y * KCHUNK;
    const int tid = threadIdx.x;
    const int tm = tid >> 4;          // 0..15 -> rows tm*4..tm*4+3
    const int tn = tid & 15;          // 0..15 -> cols tn*8..tn*8+7

    float acc[4][8] = {{0.f}};

    for (int t = 0; t < KCHUNK / BK; t++) {
        int k0 = k_begin + t * BK;
        // stage A: 64 rows x 32 k (2 float4/thread), stored transposed
        #pragma unroll
        for (int i = 0; i < 2; i++) {
            int j = i * 256 + tid;
            int r = j >> 3;           // 0..63
            int cq = (j & 7) * 4;     // 0..28
            int m = m0 + r;
            float4 v = make_float4(0.f, 0.f, 0.f, 0.f);
            if (m < M) v = *(const float4*)(A + (size_t)m * K_ALL + k0 + cq);
            As[cq + 0][r] = v.x;
            As[cq + 1][r] = v.y;
            As[cq + 2][r] = v.z;
            As[cq + 3][r] = v.w;
        }
        // stage B: Bs[r][c] = W[(k0&127)+r][(k0>>7)*128 + c]  (4 float4/thread)
        {
            int h128 = (k0 >> 7) << 7;
            int kb = k0 & 127;
            #pragma unroll
            for (int i = 0; i < 4; i++) {
                int j = i * 256 + tid;
                int r = j >> 5;          // 0..31
                int cc = (j & 31) * 4;   // 0..124
                float4 v = *(const float4*)(W + (size_t)(kb + r) * K_ALL + h128 + cc);
                *(float4*)&Bs[r][cc] = v;
            }
        }
        __syncthreads();
        #pragma unroll 8
        for (int kk = 0; kk < BK; kk++) {
            float4 a4 = *(const float4*)&As[kk][tm * 4];
            float4 b0 = *(const float4*)&Bs[kk][tn * 8];
            float4 b1 = *(const float4*)&Bs[kk][tn * 8 + 4];
            acc[0][0] += a4.x * b0.x; acc[0][1] += a4.x * b0.y;
            acc[0][2] += a4.x * b0.z; acc[0][3] += a4.x * b0.w;
            acc[0][4] += a4.x * b1.x; acc[0][5] += a4.x * b1.y;
            acc[0][6] += a4.x * b1.z; acc[0][7] += a4.x * b1.w;
            acc[1][0] += a4.y * b0.x; acc[1][1] += a4.y * b0.y;
            acc[1][2] += a4.y * b0.z; acc[1][3] += a4.y * b0.w;
            acc[1][4] += a4.y * b1.x; acc[1][5] += a4.y * b1.y;
            acc[1][6] += a4.y * b1.z; acc[1][7] += a4.y * b1.w;
            acc[2][0] += a4.z * b0.x; acc[2][1] += a4.z * b0.y;
            acc[2][2] += a4.z * b0.z; acc[2][3] += a4.z * b0.w;
            acc[2][4] += a4.z * b1.x; acc[2][5] += a4.z * b1.y;
            acc[2][6] += a4.z * b1.z; acc[2][7] += a4.z * b1.w;
            acc[3][0] += a4.w * b0.x; acc[3][1] += a4.w * b0.y;
            acc[3][2] += a4.w * b0.z; acc[3][3] += a4.w * b0.w;
            acc[3][4] += a4.w * b1.x; acc[3][5] += a4.w * b1.y;
            acc[3][6] += a4.w * b1.z; acc[3][7] += a4.w * b1.w;
        }
        __syncthreads();
    }

    float* pp = part + (size_t)blockIdx.y * M * D;
    #pragma unroll
    for (int i = 0; i < 4; i++) {
        int m = m0 + tm * 4 + i;
        if (m < M) {
            *(float4*)(pp + (size_t)m * D + tn * 8) =
                make_float4(acc[i][0], acc[i][1], acc[i][2], acc[i][3]);
            *(float4*)(pp + (size_t)m * D + tn * 8 + 4) =
                make_float4(acc[i][4], acc[i][5], acc[i][6], acc[i][7]);
        }
    }
}

// out = relu((p0+p1+p2)/6 + bias)
__global__ __launch_bounds__(256) void reduce_kernel(const float* __restrict__ part,
                                                     const float* __restrict__ bias,
                                                     float* __restrict__ out, int M) {
    int idx = blockIdx.x * blockDim.x + threadIdx.x;   // float4 index
    int total = M * (D / 4);
    if (idx >= total) return;
    const float4* p0 = (const float4*)part;
    const float4* p1 = p0 + (size_t)M * (D / 4);
    const float4* p2 = p1 + (size_t)M * (D / 4);
    float4 v0 = p0[idx], v1 = p1[idx], v2 = p2[idx];
    float4 bv = *(const float4*)(bias + (idx & (D / 4 - 1)) * 4);
    const float inv6 = 1.0f / 6.0f;
    float4 r;
    r.x = (v0.x + v1.x + v2.x) * inv6 + bv.x;
    r.y = (v0.y + v1.y + v2.y) * inv6 + bv.y;
    r.z = (v0.z + v1.z + v2.z) * inv6 + bv.z;
    r.w = (v0.w + v1.w + v2.w) * inv6 + bv.w;
    r.x = r.x > 0.f ? r.x : 0.f;
    r.y = r.y > 0.f ? r.y : 0.f;
    r.z = r.z > 0.f ? r.z : 0.f;
    r.w = r.w > 0.f ? r.w : 0.f;
    ((float4*)out)[idx] = r;
}

// ---------------- host ----------------

extern "C" void kernel_launch(void* const* d_in, const int* in_sizes, int n_in,
                              void* d_out, int out_size, void* d_ws, size_t ws_size,
                              hipStream_t stream) {
    const float* x_in = (const float*)d_in[0];
    const int* ei = (const int*)d_in[1];
    int N = in_sizes[0] / D;
    int E = in_sizes[1] / 2;
    const int* srcp = ei;
    const int* dstp = ei + E;

    float* ws = (float*)d_ws;
    float* bufA = ws;
    float* bufB = bufA + (size_t)N * D;
    float* abuf = bufB + (size_t)N * D;
    float* wa = abuf + (size_t)N * 12;
    float* agg = wa + 128 * 12;
    float* part = agg + (size_t)N * (H * D);
    int* rowptr = (int*)(part + (size_t)SPLITK * N * D);
    int* deg = rowptr + (N + 1);
    int* col = deg + N;

    // CSR build
    hipMemsetAsync(deg, 0, (size_t)N * sizeof(int), stream);
    hist_kernel<<<(E + 255) / 256, 256, 0, stream>>>(dstp, deg, E);
    scan_kernel<<<1, 1024, 0, stream>>>(deg, rowptr, N);
    scatter_kernel<<<(E + 255) / 256, 256, 0, stream>>>(srcp, dstp, rowptr, col, E);

    const float* xcur = x_in;
    for (int l = 0; l < 4; l++) {
        const float* W   = (const float*)d_in[2 + 4 * l];
        const float* as_ = (const float*)d_in[3 + 4 * l];
        const float* ad_ = (const float*)d_in[4 + 4 * l];
        const float* b   = (const float*)d_in[5 + 4 * l];
        float* xout = (l == 3) ? (float*)d_out : ((l & 1) ? bufB : bufA);

        fold_att_kernel<<<6, 256, 0, stream>>>(W, as_, ad_, wa);
        compute_a_kernel<<<(N + 3) / 4, 256, 0, stream>>>(xcur, wa, abuf, N);
        aggregate_kernel<<<(N + 3) / 4, 256, 0, stream>>>(xcur, abuf, rowptr, deg, col, agg, N);
        gemm_part_kernel<<<dim3((N + BM - 1) / BM, SPLITK), 256, 0, stream>>>(agg, W, part, N);
        reduce_kernel<<<(N * (D / 4) + 255) / 256, 256, 0, stream>>>(part, b, xout, N);

        xcur = xout;
    }
}

// Round 5
// 357.177 us; speedup vs baseline: 26.2337x; 1.0972x over previous
//
#include <hip/hip_runtime.h>
#include <math.h>

#define H 6
#define D 128
#define K_ALL (H * D)   // 768

// ---------------- CSR build ----------------

__global__ __launch_bounds__(256) void hist_kernel(const int* __restrict__ dst,
                                                   int* __restrict__ deg, int E) {
    int e = blockIdx.x * blockDim.x + threadIdx.x;
    if (e < E) atomicAdd(&deg[dst[e]], 1);
}

__global__ __launch_bounds__(1024) void scan_kernel(const int* __restrict__ deg,
                                                    int* __restrict__ rowptr, int n) {
    __shared__ int wsum[16];
    __shared__ int carry;
    if (threadIdx.x == 0) carry = 0;
    __syncthreads();
    int lane = threadIdx.x & 63;
    int wv = (int)(threadIdx.x >> 6);
    for (int base = 0; base < n; base += 1024) {
        int i = base + (int)threadIdx.x;
        int v = (i < n) ? deg[i] : 0;
        int s = v;
        #pragma unroll
        for (int off = 1; off < 64; off <<= 1) {
            int t = __shfl_up(s, off, 64);
            if (lane >= off) s += t;
        }
        if (lane == 63) wsum[wv] = s;
        __syncthreads();
        if (threadIdx.x < 16) {
            int t = wsum[threadIdx.x];
            #pragma unroll
            for (int off = 1; off < 16; off <<= 1) {
                int u = __shfl_up(t, off, 64);
                if ((int)threadIdx.x >= off) t += u;
            }
            wsum[threadIdx.x] = t;
        }
        __syncthreads();
        int woff = (wv > 0) ? wsum[wv - 1] : 0;
        if (i < n) rowptr[i] = carry + woff + s - v;
        __syncthreads();
        if (threadIdx.x == 0) carry += wsum[15];
        __syncthreads();
    }
}

__global__ __launch_bounds__(256) void scatter_kernel(const int* __restrict__ src,
                                                      const int* __restrict__ dst,
                                                      int* __restrict__ rowcur,
                                                      int* __restrict__ col, int E) {
    int e = blockIdx.x * blockDim.x + threadIdx.x;
    if (e < E) {
        int p = atomicAdd(&rowcur[dst[e]], 1);
        col[p] = src[e];
    }
}

// ---------------- fold all layers' att vectors into wa_all[4][128*12] ----------------

struct FoldArgs {
    const float* W[4];
    const float* as[4];
    const float* ad[4];
};

__global__ __launch_bounds__(256) void fold_all_kernel(FoldArgs fa, float* __restrict__ wa_all) {
    int t = blockIdx.x * blockDim.x + threadIdx.x;
    if (t >= 4 * 128 * 12) return;
    int l = t / 1536;
    int r = t % 1536;
    int k = r / 12, j = r % 12;
    int h = (j < 6) ? j : (j - 6);
    const float* att = (j < 6) ? fa.as[l] : fa.ad[l];
    const float* wrow = fa.W[l] + (size_t)k * K_ALL + h * D;
    const float* arow = att + h * D;
    float s = 0.f;
    #pragma unroll 8
    for (int c = 0; c < D; c++) s += wrow[c] * arow[c];
    wa_all[(size_t)l * 1536 + k * 12 + j] = s;
}

// a[n][j] = x[n,:] @ wa[:,j]   (one wave per node) — used only for layer 0
__global__ __launch_bounds__(256) void compute_a_kernel(const float* __restrict__ x,
                                                        const float* __restrict__ wa,
                                                        float* __restrict__ a, int n_nodes) {
    __shared__ float swa[128 * 12];
    for (int i = threadIdx.x; i < 128 * 12; i += 256) swa[i] = wa[i];
    __syncthreads();
    int wid = (int)((blockIdx.x * blockDim.x + threadIdx.x) >> 6);
    int lane = threadIdx.x & 63;
    if (wid >= n_nodes) return;
    float x0 = x[(size_t)wid * D + lane];
    float x1 = x[(size_t)wid * D + 64 + lane];
    #pragma unroll
    for (int j = 0; j < 12; j++) {
        float p = x0 * swa[lane * 12 + j] + x1 * swa[(64 + lane) * 12 + j];
        #pragma unroll
        for (int off = 32; off; off >>= 1) p += __shfl_xor(p, off, 64);
        if (lane == 0) a[(size_t)wid * 12 + j] = p;
    }
}

__device__ __forceinline__ float rlf(float v, int j) {
    return __int_as_float(__builtin_amdgcn_readlane(__float_as_int(v), j));
}

// One wave per dst node; lane-parallel softmax; readlane-broadcast, 2-deep
// software-pipelined x-gather; channels c = 2*lane, 2*lane+1 (float2).
__global__ __launch_bounds__(256) void aggregate_kernel(const float* __restrict__ x,
                                                        const float* __restrict__ a,
                                                        const int* __restrict__ rowend,
                                                        const int* __restrict__ deg_,
                                                        const int* __restrict__ col,
                                                        float* __restrict__ agg, int n_nodes) {
    int wid = (int)((blockIdx.x * blockDim.x + threadIdx.x) >> 6);
    int lane = threadIdx.x & 63;
    if (wid >= n_nodes) return;
    const int n = wid;
    const int deg = deg_[n];
    const int start = rowend[n] - deg;
    const int nent = deg + 1;

    float adst[H];
    #pragma unroll
    for (int h = 0; h < H; h++) adst[h] = a[(size_t)n * 12 + 6 + h];

    float* og = agg + (size_t)n * (H * D);

    if (nent <= 64) {
        const bool act = lane < nent;
        int s = n;                          // lane 'deg' = self loop
        if (lane < deg) s = col[start + lane];

        const float* as_ = a + (size_t)s * 12;
        float4 v0 = *(const float4*)as_;
        float2 v1 = *(const float2*)(as_ + 4);
        float e0 = v0.x + adst[0], e1 = v0.y + adst[1], e2 = v0.z + adst[2];
        float e3 = v0.w + adst[3], e4 = v1.x + adst[4], e5 = v1.y + adst[5];
        e0 = e0 > 0.f ? e0 : 0.2f * e0;  e1 = e1 > 0.f ? e1 : 0.2f * e1;
        e2 = e2 > 0.f ? e2 : 0.2f * e2;  e3 = e3 > 0.f ? e3 : 0.2f * e3;
        e4 = e4 > 0.f ? e4 : 0.2f * e4;  e5 = e5 > 0.f ? e5 : 0.2f * e5;
        if (!act) { e0 = e1 = e2 = e3 = e4 = e5 = -1e30f; }

        float m0 = e0, m1 = e1, m2 = e2, m3 = e3, m4 = e4, m5 = e5;
        #pragma unroll
        for (int off = 32; off; off >>= 1) {
            m0 = fmaxf(m0, __shfl_xor(m0, off, 64));
            m1 = fmaxf(m1, __shfl_xor(m1, off, 64));
            m2 = fmaxf(m2, __shfl_xor(m2, off, 64));
            m3 = fmaxf(m3, __shfl_xor(m3, off, 64));
            m4 = fmaxf(m4, __shfl_xor(m4, off, 64));
            m5 = fmaxf(m5, __shfl_xor(m5, off, 64));
        }
        float w0 = act ? __expf(e0 - m0) : 0.f;
        float w1 = act ? __expf(e1 - m1) : 0.f;
        float w2 = act ? __expf(e2 - m2) : 0.f;
        float w3 = act ? __expf(e3 - m3) : 0.f;
        float w4 = act ? __expf(e4 - m4) : 0.f;
        float w5 = act ? __expf(e5 - m5) : 0.f;
        float d0 = w0, d1 = w1, d2 = w2, d3 = w3, d4 = w4, d5 = w5;
        #pragma unroll
        for (int off = 32; off; off >>= 1) {
            d0 += __shfl_xor(d0, off, 64);  d1 += __shfl_xor(d1, off, 64);
            d2 += __shfl_xor(d2, off, 64);  d3 += __shfl_xor(d3, off, 64);
            d4 += __shfl_xor(d4, off, 64);  d5 += __shfl_xor(d5, off, 64);
        }
        w0 *= 1.f / (d0 + 1e-16f);  w1 *= 1.f / (d1 + 1e-16f);
        w2 *= 1.f / (d2 + 1e-16f);  w3 *= 1.f / (d3 + 1e-16f);
        w4 *= 1.f / (d4 + 1e-16f);  w5 *= 1.f / (d5 + 1e-16f);

        float a00 = 0, a01 = 0, a02 = 0, a03 = 0, a04 = 0, a05 = 0;
        float a10 = 0, a11 = 0, a12 = 0, a13 = 0, a14 = 0, a15 = 0;
        const float* xb = x + (lane << 1);

        float2 xa, xbv;
        {
            int s0 = __builtin_amdgcn_readlane(s, 0);
            xa = *(const float2*)(xb + (size_t)s0 * D);
        }
        xbv = make_float2(0.f, 0.f);
        if (nent > 1) {
            int s1 = __builtin_amdgcn_readlane(s, 1);
            xbv = *(const float2*)(xb + (size_t)s1 * D);
        }
        for (int j = 0; j < nent; j += 2) {
            float2 xn0 = make_float2(0.f, 0.f), xn1 = make_float2(0.f, 0.f);
            if (j + 2 < nent) {
                int s2 = __builtin_amdgcn_readlane(s, j + 2);
                xn0 = *(const float2*)(xb + (size_t)s2 * D);
            }
            if (j + 3 < nent) {
                int s3 = __builtin_amdgcn_readlane(s, j + 3);
                xn1 = *(const float2*)(xb + (size_t)s3 * D);
            }
            {
                float b0 = rlf(w0, j), b1 = rlf(w1, j), b2 = rlf(w2, j);
                float b3 = rlf(w3, j), b4 = rlf(w4, j), b5 = rlf(w5, j);
                a00 += b0 * xa.x; a10 += b0 * xa.y;
                a01 += b1 * xa.x; a11 += b1 * xa.y;
                a02 += b2 * xa.x; a12 += b2 * xa.y;
                a03 += b3 * xa.x; a13 += b3 * xa.y;
                a04 += b4 * xa.x; a14 += b4 * xa.y;
                a05 += b5 * xa.x; a15 += b5 * xa.y;
            }
            if (j + 1 < nent) {
                float b0 = rlf(w0, j + 1), b1 = rlf(w1, j + 1), b2 = rlf(w2, j + 1);
                float b3 = rlf(w3, j + 1), b4 = rlf(w4, j + 1), b5 = rlf(w5, j + 1);
                a00 += b0 * xbv.x; a10 += b0 * xbv.y;
                a01 += b1 * xbv.x; a11 += b1 * xbv.y;
                a02 += b2 * xbv.x; a12 += b2 * xbv.y;
                a03 += b3 * xbv.x; a13 += b3 * xbv.y;
                a04 += b4 * xbv.x; a14 += b4 * xbv.y;
                a05 += b5 * xbv.x; a15 += b5 * xbv.y;
            }
            xa = xn0; xbv = xn1;
        }
        int c = lane << 1;
        *(float2*)(og + 0 * D + c) = make_float2(a00, a10);
        *(float2*)(og + 1 * D + c) = make_float2(a01, a11);
        *(float2*)(og + 2 * D + c) = make_float2(a02, a12);
        *(float2*)(og + 3 * D + c) = make_float2(a03, a13);
        *(float2*)(og + 4 * D + c) = make_float2(a04, a14);
        *(float2*)(og + 5 * D + c) = make_float2(a05, a15);
    } else {
        // slow fallback (deg >= 64)
        float m[H];
        #pragma unroll
        for (int h = 0; h < H; h++) {
            float e = a[(size_t)n * 12 + h] + adst[h];
            m[h] = (e > 0.f) ? e : 0.2f * e;
        }
        for (int j = 0; j < deg; j++) {
            int s = col[start + j];
            #pragma unroll
            for (int h = 0; h < H; h++) {
                float e = a[(size_t)s * 12 + h] + adst[h];
                e = (e > 0.f) ? e : 0.2f * e;
                m[h] = fmaxf(m[h], e);
            }
        }
        float d[H] = {0, 0, 0, 0, 0, 0};
        float acc0[H] = {0, 0, 0, 0, 0, 0};
        float acc1[H] = {0, 0, 0, 0, 0, 0};
        int c0 = lane, c1 = 64 + lane;
        for (int j = 0; j <= deg; j++) {
            int s = (j < deg) ? col[start + j] : n;
            float w[H];
            #pragma unroll
            for (int h = 0; h < H; h++) {
                float e = a[(size_t)s * 12 + h] + adst[h];
                e = (e > 0.f) ? e : 0.2f * e;
                w[h] = __expf(e - m[h]);
                d[h] += w[h];
            }
            float xv0 = x[(size_t)s * D + c0];
            float xv1 = x[(size_t)s * D + c1];
            #pragma unroll
            for (int h = 0; h < H; h++) {
                acc0[h] += w[h] * xv0;
                acc1[h] += w[h] * xv1;
            }
        }
        #pragma unroll
        for (int h = 0; h < H; h++) {
            float inv = 1.0f / (d[h] + 1e-16f);
            og[h * D + c0] = acc0[h] * inv;
            og[h * D + c1] = acc1[h] * inv;
        }
    }
}

// ---------------- GEMM: part[ky][m][c] = sum_{k in chunk ky} agg[m][k]*B[k][c] ----------------
// B[k][c] = W[k&127][(k>>7)*128 + c]
// 4x(4+4) micro-tile: B-fragment cols split as {tn*4, 64+tn*4} -> LDS read
// addresses at 16B stride -> 2-way bank aliasing (free) instead of 4-way.
#define BM 64
#define BN 128
#define BK 32
#define SPLITK 3
#define KCHUNK (K_ALL / SPLITK)   // 256

__global__ __launch_bounds__(256) void gemm_part_kernel(const float* __restrict__ A,
                                                        const float* __restrict__ W,
                                                        float* __restrict__ part, int M) {
    __shared__ float As[BK][BM + 4];   // transposed A; row stride 68 floats
    __shared__ float Bs[BK][BN];
    const int m0 = blockIdx.x * BM;
    const int k_begin = blockIdx.y * KCHUNK;
    const int tid = threadIdx.x;
    const int tm = tid >> 4;          // 0..15 -> rows tm*4..tm*4+3
    const int tn = tid & 15;          // 0..15 -> cols {tn*4..+3} and {64+tn*4..+3}

    float acc[4][8] = {{0.f}};

    for (int t = 0; t < KCHUNK / BK; t++) {
        int k0 = k_begin + t * BK;
        // stage A: 64 rows x 32 k (2 float4/thread), stored transposed
        #pragma unroll
        for (int i = 0; i < 2; i++) {
            int j = i * 256 + tid;
            int r = j >> 3;           // 0..63
            int cq = (j & 7) * 4;     // 0..28
            int m = m0 + r;
            float4 v = make_float4(0.f, 0.f, 0.f, 0.f);
            if (m < M) v = *(const float4*)(A + (size_t)m * K_ALL + k0 + cq);
            As[cq + 0][r] = v.x;
            As[cq + 1][r] = v.y;
            As[cq + 2][r] = v.z;
            As[cq + 3][r] = v.w;
        }
        // stage B: Bs[r][c] = W[(k0&127)+r][(k0>>7)*128 + c]  (4 float4/thread)
        {
            int h128 = (k0 >> 7) << 7;
            int kb = k0 & 127;
            #pragma unroll
            for (int i = 0; i < 4; i++) {
                int j = i * 256 + tid;
                int r = j >> 5;          // 0..31
                int cc = (j & 31) * 4;   // 0..124
                float4 v = *(const float4*)(W + (size_t)(kb + r) * K_ALL + h128 + cc);
                *(float4*)&Bs[r][cc] = v;
            }
        }
        __syncthreads();
        #pragma unroll 8
        for (int kk = 0; kk < BK; kk++) {
            float4 a4 = *(const float4*)&As[kk][tm * 4];
            float4 b0 = *(const float4*)&Bs[kk][tn * 4];
            float4 b1 = *(const float4*)&Bs[kk][64 + tn * 4];
            acc[0][0] += a4.x * b0.x; acc[0][1] += a4.x * b0.y;
            acc[0][2] += a4.x * b0.z; acc[0][3] += a4.x * b0.w;
            acc[0][4] += a4.x * b1.x; acc[0][5] += a4.x * b1.y;
            acc[0][6] += a4.x * b1.z; acc[0][7] += a4.x * b1.w;
            acc[1][0] += a4.y * b0.x; acc[1][1] += a4.y * b0.y;
            acc[1][2] += a4.y * b0.z; acc[1][3] += a4.y * b0.w;
            acc[1][4] += a4.y * b1.x; acc[1][5] += a4.y * b1.y;
            acc[1][6] += a4.y * b1.z; acc[1][7] += a4.y * b1.w;
            acc[2][0] += a4.z * b0.x; acc[2][1] += a4.z * b0.y;
            acc[2][2] += a4.z * b0.z; acc[2][3] += a4.z * b0.w;
            acc[2][4] += a4.z * b1.x; acc[2][5] += a4.z * b1.y;
            acc[2][6] += a4.z * b1.z; acc[2][7] += a4.z * b1.w;
            acc[3][0] += a4.w * b0.x; acc[3][1] += a4.w * b0.y;
            acc[3][2] += a4.w * b0.z; acc[3][3] += a4.w * b0.w;
            acc[3][4] += a4.w * b1.x; acc[3][5] += a4.w * b1.y;
            acc[3][6] += a4.w * b1.z; acc[3][7] += a4.w * b1.w;
        }
        __syncthreads();
    }

    float* pp = part + (size_t)blockIdx.y * M * D;
    #pragma unroll
    for (int i = 0; i < 4; i++) {
        int m = m0 + tm * 4 + i;
        if (m < M) {
            *(float4*)(pp + (size_t)m * D + tn * 4) =
                make_float4(acc[i][0], acc[i][1], acc[i][2], acc[i][3]);
            *(float4*)(pp + (size_t)m * D + 64 + tn * 4) =
                make_float4(acc[i][4], acc[i][5], acc[i][6], acc[i][7]);
        }
    }
}

// fused: x = relu((p0+p1+p2)/6 + bias); optionally a[n][j] = x[n,:] @ wa[:,j]
// one wave per node, lane holds channels 2*lane, 2*lane+1
__global__ __launch_bounds__(256) void reduce_a_kernel(const float* __restrict__ part,
                                                       const float* __restrict__ bias,
                                                       const float* __restrict__ wa,
                                                       float* __restrict__ xout,
                                                       float* __restrict__ a,
                                                       int M, int write_a) {
    __shared__ float swa[128 * 12];
    if (write_a) {
        for (int i = threadIdx.x; i < 128 * 12; i += 256) swa[i] = wa[i];
        __syncthreads();
    }
    int wid = (int)((blockIdx.x * blockDim.x + threadIdx.x) >> 6);
    int lane = threadIdx.x & 63;
    if (wid >= M) return;
    int c = lane << 1;
    const float* p0 = part + (size_t)wid * D + c;
    const float* p1 = p0 + (size_t)M * D;
    const float* p2 = p1 + (size_t)M * D;
    float2 v0 = *(const float2*)p0;
    float2 v1 = *(const float2*)p1;
    float2 v2 = *(const float2*)p2;
    float2 bv = *(const float2*)(bias + c);
    const float inv6 = 1.0f / 6.0f;
    float rx = (v0.x + v1.x + v2.x) * inv6 + bv.x;
    float ry = (v0.y + v1.y + v2.y) * inv6 + bv.y;
    rx = rx > 0.f ? rx : 0.f;
    ry = ry > 0.f ? ry : 0.f;
    *(float2*)(xout + (size_t)wid * D + c) = make_float2(rx, ry);

    if (write_a) {
        #pragma unroll
        for (int j = 0; j < 12; j++) {
            float p = rx * swa[c * 12 + j] + ry * swa[(c + 1) * 12 + j];
            #pragma unroll
            for (int off = 32; off; off >>= 1) p += __shfl_xor(p, off, 64);
            if (lane == 0) a[(size_t)wid * 12 + j] = p;
        }
    }
}

// ---------------- host ----------------

extern "C" void kernel_launch(void* const* d_in, const int* in_sizes, int n_in,
                              void* d_out, int out_size, void* d_ws, size_t ws_size,
                              hipStream_t stream) {
    const float* x_in = (const float*)d_in[0];
    const int* ei = (const int*)d_in[1];
    int N = in_sizes[0] / D;
    int E = in_sizes[1] / 2;
    const int* srcp = ei;
    const int* dstp = ei + E;

    float* ws = (float*)d_ws;
    float* bufA = ws;
    float* bufB = bufA + (size_t)N * D;
    float* abuf = bufB + (size_t)N * D;
    float* wa_all = abuf + (size_t)N * 12;
    float* agg = wa_all + 4 * 1536;
    float* part = agg + (size_t)N * (H * D);
    int* rowptr = (int*)(part + (size_t)SPLITK * N * D);
    int* deg = rowptr + (N + 1);
    int* col = deg + N;

    // CSR build
    hipMemsetAsync(deg, 0, (size_t)N * sizeof(int), stream);
    hist_kernel<<<(E + 255) / 256, 256, 0, stream>>>(dstp, deg, E);
    scan_kernel<<<1, 1024, 0, stream>>>(deg, rowptr, N);
    scatter_kernel<<<(E + 255) / 256, 256, 0, stream>>>(srcp, dstp, rowptr, col, E);

    // fold all 4 layers' attention vectors
    FoldArgs fa;
    for (int l = 0; l < 4; l++) {
        fa.W[l]  = (const float*)d_in[2 + 4 * l];
        fa.as[l] = (const float*)d_in[3 + 4 * l];
        fa.ad[l] = (const float*)d_in[4 + 4 * l];
    }
    fold_all_kernel<<<24, 256, 0, stream>>>(fa, wa_all);

    // layer 0 attention logits
    compute_a_kernel<<<(N + 3) / 4, 256, 0, stream>>>(x_in, wa_all, abuf, N);

    const float* xcur = x_in;
    for (int l = 0; l < 4; l++) {
        const float* W = (const float*)d_in[2 + 4 * l];
        const float* b = (const float*)d_in[5 + 4 * l];
        float* xout = (l == 3) ? (float*)d_out : ((l & 1) ? bufB : bufA);

        aggregate_kernel<<<(N + 3) / 4, 256, 0, stream>>>(xcur, abuf, rowptr, deg, col, agg, N);
        gemm_part_kernel<<<dim3((N + BM - 1) / BM, SPLITK), 256, 0, stream>>>(agg, W, part, N);
        reduce_a_kernel<<<(N + 3) / 4, 256, 0, stream>>>(part, b,
                                                         wa_all + (l + 1) * 1536,
                                                         xout, abuf, N, (l < 3) ? 1 : 0);
        xcur = xout;
    }
}

// Round 6
// 251.393 us; speedup vs baseline: 37.2727x; 1.4208x over previous
//
#include <hip/hip_runtime.h>
#include <hip/hip_fp16.h>
#include <math.h>

#define H 6
#define D 128
#define K_ALL (H * D)   // 768
#define TSTEPS 24       // K_ALL / 32

typedef _Float16 f16x8 __attribute__((ext_vector_type(8)));
typedef float f32x4 __attribute__((ext_vector_type(4)));

// ---------------- CSR build ----------------

__global__ __launch_bounds__(256) void hist_kernel(const int* __restrict__ dst,
                                                   int* __restrict__ deg, int E) {
    int e = blockIdx.x * blockDim.x + threadIdx.x;
    if (e < E) atomicAdd(&deg[dst[e]], 1);
}

__global__ __launch_bounds__(1024) void scan_kernel(const int* __restrict__ deg,
                                                    int* __restrict__ rowptr, int n) {
    __shared__ int wsum[16];
    __shared__ int carry;
    if (threadIdx.x == 0) carry = 0;
    __syncthreads();
    int lane = threadIdx.x & 63;
    int wv = (int)(threadIdx.x >> 6);
    for (int base = 0; base < n; base += 1024) {
        int i = base + (int)threadIdx.x;
        int v = (i < n) ? deg[i] : 0;
        int s = v;
        #pragma unroll
        for (int off = 1; off < 64; off <<= 1) {
            int t = __shfl_up(s, off, 64);
            if (lane >= off) s += t;
        }
        if (lane == 63) wsum[wv] = s;
        __syncthreads();
        if (threadIdx.x < 16) {
            int t = wsum[threadIdx.x];
            #pragma unroll
            for (int off = 1; off < 16; off <<= 1) {
                int u = __shfl_up(t, off, 64);
                if ((int)threadIdx.x >= off) t += u;
            }
            wsum[threadIdx.x] = t;
        }
        __syncthreads();
        int woff = (wv > 0) ? wsum[wv - 1] : 0;
        if (i < n) rowptr[i] = carry + woff + s - v;
        __syncthreads();
        if (threadIdx.x == 0) carry += wsum[15];
        __syncthreads();
    }
}

__global__ __launch_bounds__(256) void scatter_kernel(const int* __restrict__ src,
                                                      const int* __restrict__ dst,
                                                      int* __restrict__ rowcur,
                                                      int* __restrict__ col, int E) {
    int e = blockIdx.x * blockDim.x + threadIdx.x;
    if (e < E) {
        int p = atomicAdd(&rowcur[dst[e]], 1);
        col[p] = src[e];
    }
}

// ---------------- one-time weight prep ----------------

struct FoldArgs {
    const float* W[4];
    const float* as[4];
    const float* ad[4];
};

// wa_all[l][k][j] = sum_c W_l[k][h*128+c] * att[h][c]
__global__ __launch_bounds__(256) void fold_all_kernel(FoldArgs fa, float* __restrict__ wa_all) {
    int t = blockIdx.x * blockDim.x + threadIdx.x;
    if (t >= 4 * 128 * 12) return;
    int l = t / 1536;
    int r = t % 1536;
    int k = r / 12, j = r % 12;
    int h = (j < 6) ? j : (j - 6);
    const float* att = (j < 6) ? fa.as[l] : fa.ad[l];
    const float* wrow = fa.W[l] + (size_t)k * K_ALL + h * D;
    const float* arow = att + h * D;
    float s = 0.f;
    #pragma unroll 8
    for (int c = 0; c < D; c++) s += wrow[c] * arow[c];
    wa_all[(size_t)l * 1536 + k * 12 + j] = s;
}

// B fragment pack: bf[l][t][ct][lane][j] = B[k][c], k = t*32 + (lane>>4)*8 + j,
// c = ct*16 + (lane&15), where B[k][c] = W[k&127][(k>>7)*128 + c].
// Same k-convention as the A pack below -> MFMA result independent of the
// instruction's internal k order.
__global__ __launch_bounds__(256) void fold_bf_kernel(FoldArgs fa, __half* __restrict__ bf) {
    int tid = blockIdx.x * blockDim.x + threadIdx.x;
    if (tid >= 4 * TSTEPS * 8 * 64) return;
    int l63 = tid & 63;
    int ct = (tid >> 6) & 7;
    int t = (tid >> 9) % TSTEPS;
    int layer = tid / (TSTEPS * 8 * 64);
    const float* W = fa.W[layer];
    int c = ct * 16 + (l63 & 15);
    f16x8 v;
    #pragma unroll
    for (int j = 0; j < 8; j++) {
        int k = t * 32 + ((l63 >> 4) << 3) + j;
        v[j] = (_Float16)W[(size_t)(k & 127) * K_ALL + ((k >> 7) << 7) + c];
    }
    *(f16x8*)(bf + ((size_t)tid << 3)) = v;
}

// a[n][j] = x[n,:] @ wa[:,j]   (one wave per node)
__global__ __launch_bounds__(256) void compute_a_kernel(const float* __restrict__ x,
                                                        const float* __restrict__ wa,
                                                        float* __restrict__ a, int n_nodes) {
    __shared__ float swa[128 * 12];
    for (int i = threadIdx.x; i < 128 * 12; i += 256) swa[i] = wa[i];
    __syncthreads();
    int wid = (int)((blockIdx.x * blockDim.x + threadIdx.x) >> 6);
    int lane = threadIdx.x & 63;
    if (wid >= n_nodes) return;
    float x0 = x[(size_t)wid * D + lane];
    float x1 = x[(size_t)wid * D + 64 + lane];
    #pragma unroll
    for (int j = 0; j < 12; j++) {
        float p = x0 * swa[lane * 12 + j] + x1 * swa[(64 + lane) * 12 + j];
        #pragma unroll
        for (int off = 32; off; off >>= 1) p += __shfl_xor(p, off, 64);
        if (lane == 0) a[(size_t)wid * 12 + j] = p;
    }
}

__device__ __forceinline__ float rlf(float v, int j) {
    return __int_as_float(__builtin_amdgcn_readlane(__float_as_int(v), j));
}

// One wave per dst node; lane-parallel softmax; readlane-broadcast pipelined
// x-gather. Writes the aggregation result DIRECTLY as f16 MFMA A-fragments:
// aggf[mtile64][t][rg][fraglane][elem], value(k=h*128+c) at
// fraglane=(n&15)+((k&31)>>3)*16, elem=k&7, t=k>>5.
__global__ __launch_bounds__(256) void aggregate_kernel(const float* __restrict__ x,
                                                        const float* __restrict__ a,
                                                        const int* __restrict__ rowend,
                                                        const int* __restrict__ deg_,
                                                        const int* __restrict__ col,
                                                        __half* __restrict__ aggf, int n_nodes) {
    int wid = (int)((blockIdx.x * blockDim.x + threadIdx.x) >> 6);
    int lane = threadIdx.x & 63;
    if (wid >= n_nodes) return;
    const int n = wid;
    const int deg = deg_[n];
    const int start = rowend[n] - deg;
    const int nent = deg + 1;

    const int mt64 = n >> 6;
    const int rg = (n >> 4) & 3;
    const int rr = n & 15;

    float adst[H];
    #pragma unroll
    for (int h = 0; h < H; h++) adst[h] = a[(size_t)n * 12 + 6 + h];

    if (nent <= 64) {
        const bool act = lane < nent;
        int s = n;                          // lane 'deg' = self loop
        if (lane < deg) s = col[start + lane];

        const float* as_ = a + (size_t)s * 12;
        float4 v0 = *(const float4*)as_;
        float2 v1 = *(const float2*)(as_ + 4);
        float e0 = v0.x + adst[0], e1 = v0.y + adst[1], e2 = v0.z + adst[2];
        float e3 = v0.w + adst[3], e4 = v1.x + adst[4], e5 = v1.y + adst[5];
        e0 = e0 > 0.f ? e0 : 0.2f * e0;  e1 = e1 > 0.f ? e1 : 0.2f * e1;
        e2 = e2 > 0.f ? e2 : 0.2f * e2;  e3 = e3 > 0.f ? e3 : 0.2f * e3;
        e4 = e4 > 0.f ? e4 : 0.2f * e4;  e5 = e5 > 0.f ? e5 : 0.2f * e5;
        if (!act) { e0 = e1 = e2 = e3 = e4 = e5 = -1e30f; }

        float m0 = e0, m1 = e1, m2 = e2, m3 = e3, m4 = e4, m5 = e5;
        #pragma unroll
        for (int off = 32; off; off >>= 1) {
            m0 = fmaxf(m0, __shfl_xor(m0, off, 64));
            m1 = fmaxf(m1, __shfl_xor(m1, off, 64));
            m2 = fmaxf(m2, __shfl_xor(m2, off, 64));
            m3 = fmaxf(m3, __shfl_xor(m3, off, 64));
            m4 = fmaxf(m4, __shfl_xor(m4, off, 64));
            m5 = fmaxf(m5, __shfl_xor(m5, off, 64));
        }
        float w0 = act ? __expf(e0 - m0) : 0.f;
        float w1 = act ? __expf(e1 - m1) : 0.f;
        float w2 = act ? __expf(e2 - m2) : 0.f;
        float w3 = act ? __expf(e3 - m3) : 0.f;
        float w4 = act ? __expf(e4 - m4) : 0.f;
        float w5 = act ? __expf(e5 - m5) : 0.f;
        float d0 = w0, d1 = w1, d2 = w2, d3 = w3, d4 = w4, d5 = w5;
        #pragma unroll
        for (int off = 32; off; off >>= 1) {
            d0 += __shfl_xor(d0, off, 64);  d1 += __shfl_xor(d1, off, 64);
            d2 += __shfl_xor(d2, off, 64);  d3 += __shfl_xor(d3, off, 64);
            d4 += __shfl_xor(d4, off, 64);  d5 += __shfl_xor(d5, off, 64);
        }
        w0 *= 1.f / (d0 + 1e-16f);  w1 *= 1.f / (d1 + 1e-16f);
        w2 *= 1.f / (d2 + 1e-16f);  w3 *= 1.f / (d3 + 1e-16f);
        w4 *= 1.f / (d4 + 1e-16f);  w5 *= 1.f / (d5 + 1e-16f);

        float a00 = 0, a01 = 0, a02 = 0, a03 = 0, a04 = 0, a05 = 0;
        float a10 = 0, a11 = 0, a12 = 0, a13 = 0, a14 = 0, a15 = 0;
        const float* xb = x + (lane << 1);   // channels c=2*lane, 2*lane+1

        float2 xa, xbv;
        {
            int s0 = __builtin_amdgcn_readlane(s, 0);
            xa = *(const float2*)(xb + (size_t)s0 * D);
        }
        xbv = make_float2(0.f, 0.f);
        if (nent > 1) {
            int s1 = __builtin_amdgcn_readlane(s, 1);
            xbv = *(const float2*)(xb + (size_t)s1 * D);
        }
        for (int j = 0; j < nent; j += 2) {
            float2 xn0 = make_float2(0.f, 0.f), xn1 = make_float2(0.f, 0.f);
            if (j + 2 < nent) {
                int s2 = __builtin_amdgcn_readlane(s, j + 2);
                xn0 = *(const float2*)(xb + (size_t)s2 * D);
            }
            if (j + 3 < nent) {
                int s3 = __builtin_amdgcn_readlane(s, j + 3);
                xn1 = *(const float2*)(xb + (size_t)s3 * D);
            }
            {
                float b0 = rlf(w0, j), b1 = rlf(w1, j), b2 = rlf(w2, j);
                float b3 = rlf(w3, j), b4 = rlf(w4, j), b5 = rlf(w5, j);
                a00 += b0 * xa.x; a10 += b0 * xa.y;
                a01 += b1 * xa.x; a11 += b1 * xa.y;
                a02 += b2 * xa.x; a12 += b2 * xa.y;
                a03 += b3 * xa.x; a13 += b3 * xa.y;
                a04 += b4 * xa.x; a14 += b4 * xa.y;
                a05 += b5 * xa.x; a15 += b5 * xa.y;
            }
            if (j + 1 < nent) {
                float b0 = rlf(w0, j + 1), b1 = rlf(w1, j + 1), b2 = rlf(w2, j + 1);
                float b3 = rlf(w3, j + 1), b4 = rlf(w4, j + 1), b5 = rlf(w5, j + 1);
                a00 += b0 * xbv.x; a10 += b0 * xbv.y;
                a01 += b1 * xbv.x; a11 += b1 * xbv.y;
                a02 += b2 * xbv.x; a12 += b2 * xbv.y;
                a03 += b3 * xbv.x; a13 += b3 * xbv.y;
                a04 += b4 * xbv.x; a14 += b4 * xbv.y;
                a05 += b5 * xbv.x; a15 += b5 * xbv.y;
            }
            xa = xn0; xbv = xn1;
        }
        // fragment-order f16 writes: c=2*lane (+1) -> k=h*128+2*lane(+1)
        int g = (lane & 15) >> 2;
        int jj = (lane & 3) << 1;
        int lam = rr + (g << 4);
        int thi = lane >> 4;
        size_t base = (((size_t)mt64 * TSTEPS) * 4 + rg) * 512 + (size_t)lam * 8 + jj;
        // per-h t = h*4 + thi; step stride in halves = 4*512 = 2048
        *(__half2*)(aggf + base + (size_t)(0 * 4 + thi) * 2048) = __floats2half2_rn(a00, a10);
        *(__half2*)(aggf + base + (size_t)(1 * 4 + thi) * 2048) = __floats2half2_rn(a01, a11);
        *(__half2*)(aggf + base + (size_t)(2 * 4 + thi) * 2048) = __floats2half2_rn(a02, a12);
        *(__half2*)(aggf + base + (size_t)(3 * 4 + thi) * 2048) = __floats2half2_rn(a03, a13);
        *(__half2*)(aggf + base + (size_t)(4 * 4 + thi) * 2048) = __floats2half2_rn(a04, a14);
        *(__half2*)(aggf + base + (size_t)(5 * 4 + thi) * 2048) = __floats2half2_rn(a05, a15);
    } else {
        // slow fallback (deg >= 64): channels c0=lane, c1=64+lane
        float m[H];
        #pragma unroll
        for (int h = 0; h < H; h++) {
            float e = a[(size_t)n * 12 + h] + adst[h];
            m[h] = (e > 0.f) ? e : 0.2f * e;
        }
        for (int j = 0; j < deg; j++) {
            int s = col[start + j];
            #pragma unroll
            for (int h = 0; h < H; h++) {
                float e = a[(size_t)s * 12 + h] + adst[h];
                e = (e > 0.f) ? e : 0.2f * e;
                m[h] = fmaxf(m[h], e);
            }
        }
        float d[H] = {0, 0, 0, 0, 0, 0};
        float acc0[H] = {0, 0, 0, 0, 0, 0};
        float acc1[H] = {0, 0, 0, 0, 0, 0};
        int c0 = lane, c1 = 64 + lane;
        for (int j = 0; j <= deg; j++) {
            int s = (j < deg) ? col[start + j] : n;
            float w[H];
            #pragma unroll
            for (int h = 0; h < H; h++) {
                float e = a[(size_t)s * 12 + h] + adst[h];
                e = (e > 0.f) ? e : 0.2f * e;
                w[h] = __expf(e - m[h]);
                d[h] += w[h];
            }
            float xv0 = x[(size_t)s * D + c0];
            float xv1 = x[(size_t)s * D + c1];
            #pragma unroll
            for (int h = 0; h < H; h++) {
                acc0[h] += w[h] * xv0;
                acc1[h] += w[h] * xv1;
            }
        }
        int g = (lane & 31) >> 3;
        int jj = lane & 7;
        int lam = rr + (g << 4);
        int thi = lane >> 5;
        #pragma unroll
        for (int h = 0; h < H; h++) {
            float inv = 1.0f / (d[h] + 1e-16f);
            size_t i0 = (((size_t)mt64 * TSTEPS + (h * 4 + thi)) * 4 + rg) * 512 + (size_t)lam * 8 + jj;
            size_t i1 = (((size_t)mt64 * TSTEPS + (h * 4 + 2 + thi)) * 4 + rg) * 512 + (size_t)lam * 8 + jj;
            aggf[i0] = (_Float16)(acc0[h] * inv);
            aggf[i1] = (_Float16)(acc1[h] * inv);
        }
    }
}

// ---------------- MFMA GEMM: out = relu(aggf @ B / 6 + bias) ----------------
// 16 output rows per block; 4 waves, wave w owns col-tiles {2w, 2w+1}.
// No LDS, no barriers. C/D layout (HW-verified): col=lane&15, row=(lane>>4)*4+reg.
__global__ __launch_bounds__(256) void gemm_mfma_kernel(const __half* __restrict__ aggf,
                                                        const __half* __restrict__ bf,
                                                        const float* __restrict__ bias,
                                                        float* __restrict__ out, int M) {
    const int wave = (int)(threadIdx.x >> 6);
    const int lane = (int)(threadIdx.x & 63);
    const int mt64 = blockIdx.x >> 2;
    const int rg = blockIdx.x & 3;
    const int m0 = blockIdx.x << 4;

    f32x4 acc0 = {0.f, 0.f, 0.f, 0.f};
    f32x4 acc1 = {0.f, 0.f, 0.f, 0.f};

    const __half* ap = aggf + (((size_t)mt64 * TSTEPS) * 4 + rg) * 512 + (size_t)lane * 8;
    const __half* bp = bf + (size_t)(wave * 2) * 512 + (size_t)lane * 8;

    for (int t = 0; t < TSTEPS; t++) {
        f16x8 av = *(const f16x8*)(ap + (size_t)t * 2048);
        f16x8 bv0 = *(const f16x8*)(bp + (size_t)t * 4096);
        f16x8 bv1 = *(const f16x8*)(bp + (size_t)t * 4096 + 512);
        acc0 = __builtin_amdgcn_mfma_f32_16x16x32_f16(av, bv0, acc0, 0, 0, 0);
        acc1 = __builtin_amdgcn_mfma_f32_16x16x32_f16(av, bv1, acc1, 0, 0, 0);
    }

    const float inv6 = 1.0f / 6.0f;
    const int c0 = wave * 32 + (lane & 15);
    const int r0 = (lane >> 4) << 2;
    const float b0 = bias[c0];
    const float b1 = bias[c0 + 16];
    #pragma unroll
    for (int reg = 0; reg < 4; reg++) {
        int m = m0 + r0 + reg;
        if (m < M) {
            float v = acc0[reg] * inv6 + b0;
            out[(size_t)m * D + c0] = v > 0.f ? v : 0.f;
            v = acc1[reg] * inv6 + b1;
            out[(size_t)m * D + c0 + 16] = v > 0.f ? v : 0.f;
        }
    }
}

// ---------------- host ----------------

extern "C" void kernel_launch(void* const* d_in, const int* in_sizes, int n_in,
                              void* d_out, int out_size, void* d_ws, size_t ws_size,
                              hipStream_t stream) {
    const float* x_in = (const float*)d_in[0];
    const int* ei = (const int*)d_in[1];
    int N = in_sizes[0] / D;
    int E = in_sizes[1] / 2;
    const int* srcp = ei;
    const int* dstp = ei + E;

    int nt64 = (N + 63) >> 6;
    size_t aggf_halves = (size_t)nt64 * TSTEPS * 4 * 512;
    size_t bf_halves_per_layer = (size_t)TSTEPS * 8 * 512;

    float* ws = (float*)d_ws;
    float* bufA = ws;
    float* bufB = bufA + (size_t)N * D;
    float* abuf = bufB + (size_t)N * D;
    float* wa_all = abuf + (size_t)N * 12;
    __half* aggf = (__half*)(wa_all + 4 * 1536);
    __half* w16f = aggf + aggf_halves;
    int* rowptr = (int*)(w16f + 4 * bf_halves_per_layer);
    int* deg = rowptr + (N + 1);
    int* col = deg + N;

    // CSR build
    hipMemsetAsync(deg, 0, (size_t)N * sizeof(int), stream);
    hist_kernel<<<(E + 255) / 256, 256, 0, stream>>>(dstp, deg, E);
    scan_kernel<<<1, 1024, 0, stream>>>(deg, rowptr, N);
    scatter_kernel<<<(E + 255) / 256, 256, 0, stream>>>(srcp, dstp, rowptr, col, E);

    // one-time weight prep
    FoldArgs fa;
    for (int l = 0; l < 4; l++) {
        fa.W[l]  = (const float*)d_in[2 + 4 * l];
        fa.as[l] = (const float*)d_in[3 + 4 * l];
        fa.ad[l] = (const float*)d_in[4 + 4 * l];
    }
    fold_all_kernel<<<24, 256, 0, stream>>>(fa, wa_all);
    fold_bf_kernel<<<(4 * TSTEPS * 8 * 64 + 255) / 256, 256, 0, stream>>>(fa, w16f);

    // layer 0 attention logits
    compute_a_kernel<<<(N + 3) / 4, 256, 0, stream>>>(x_in, wa_all, abuf, N);

    const float* xcur = x_in;
    for (int l = 0; l < 4; l++) {
        const float* b = (const float*)d_in[5 + 4 * l];
        float* xout = (l == 3) ? (float*)d_out : ((l & 1) ? bufB : bufA);

        aggregate_kernel<<<(N + 3) / 4, 256, 0, stream>>>(xcur, abuf, rowptr, deg, col, aggf, N);
        gemm_mfma_kernel<<<(N + 15) / 16, 256, 0, stream>>>(aggf,
                                                            w16f + (size_t)l * bf_halves_per_layer,
                                                            b, xout, N);
        if (l < 3)
            compute_a_kernel<<<(N + 3) / 4, 256, 0, stream>>>(xout, wa_all + (l + 1) * 1536,
                                                              abuf, N);
        xcur = xout;
    }
}

// Round 7
// 240.705 us; speedup vs baseline: 38.9277x; 1.0444x over previous
//
#include <hip/hip_runtime.h>
#include <hip/hip_fp16.h>
#include <math.h>

#define H 6
#define D 128
#define K_ALL (H * D)   // 768
#define TSTEPS 24       // K_ALL / 32

typedef _Float16 f16x8 __attribute__((ext_vector_type(8)));
typedef float f32x4 __attribute__((ext_vector_type(4)));

// ---------------- CSR build ----------------

__global__ __launch_bounds__(256) void hist_kernel(const int* __restrict__ dst,
                                                   int* __restrict__ deg, int E) {
    int e = blockIdx.x * blockDim.x + threadIdx.x;
    if (e < E) atomicAdd(&deg[dst[e]], 1);
}

// single-pass scan: thread i owns elements [i*16, i*16+16); 2 barriers total.
__global__ __launch_bounds__(1024) void scan_kernel(const int* __restrict__ deg,
                                                    int* __restrict__ rowptr, int n) {
    __shared__ int wsum[16];
    const int tid = threadIdx.x;
    const int lane = tid & 63;
    const int wv = tid >> 6;
    const int base = tid << 4;

    int v[16];
    int tot = 0;
    #pragma unroll
    for (int k = 0; k < 16; k++) {
        int i = base + k;
        int d = (i < n) ? deg[i] : 0;
        v[k] = tot;          // exclusive prefix within thread
        tot += d;
    }
    int s = tot;
    #pragma unroll
    for (int off = 1; off < 64; off <<= 1) {
        int t = __shfl_up(s, off, 64);
        if (lane >= off) s += t;
    }
    if (lane == 63) wsum[wv] = s;
    __syncthreads();
    if (tid < 16) {
        int t = wsum[tid];
        #pragma unroll
        for (int off = 1; off < 16; off <<= 1) {
            int u = __shfl_up(t, off, 64);
            if ((int)tid >= off) t += u;
        }
        wsum[tid] = t;
    }
    __syncthreads();
    int off0 = ((wv > 0) ? wsum[wv - 1] : 0) + s - tot;  // exclusive offset of this thread
    #pragma unroll
    for (int k = 0; k < 16; k++) {
        int i = base + k;
        if (i < n) rowptr[i] = off0 + v[k];
    }
}

__global__ __launch_bounds__(256) void scatter_kernel(const int* __restrict__ src,
                                                      const int* __restrict__ dst,
                                                      int* __restrict__ rowcur,
                                                      int* __restrict__ col, int E) {
    int e = blockIdx.x * blockDim.x + threadIdx.x;
    if (e < E) {
        int p = atomicAdd(&rowcur[dst[e]], 1);
        col[p] = src[e];
    }
}

// ---------------- one-time prep (merged): wa_all(L0) + waf(L1-3) + bf(L0-3) ----------------

struct FoldArgs {
    const float* W[4];
    const float* as[4];
    const float* ad[4];
};

// blocks 0..5    : wa_all[k][j] for layer 0 (1536 values)
// blocks 6..8    : waf fragments for layers 1..3 (256 threads each, computed from W directly)
// blocks 9..200  : bf fragments for layers 0..3
__global__ __launch_bounds__(256) void prep_kernel(FoldArgs fa, float* __restrict__ wa0,
                                                   __half* __restrict__ waf,
                                                   __half* __restrict__ bf) {
    int b = blockIdx.x;
    int tid = threadIdx.x;
    if (b < 6) {
        int t = b * 256 + tid;       // < 1536
        int k = t / 12, j = t % 12;
        int h = (j < 6) ? j : (j - 6);
        const float* att = (j < 6) ? fa.as[0] : fa.ad[0];
        const float* wrow = fa.W[0] + (size_t)k * K_ALL + h * D;
        const float* arow = att + h * D;
        float s = 0.f;
        #pragma unroll 8
        for (int c = 0; c < D; c++) s += wrow[c] * arow[c];
        wa0[k * 12 + j] = s;
    } else if (b < 9) {
        // waf for layer L = b-5: frag value = wa_L[k][j], j=lane&15 (<12 else 0),
        // k = t*32 + (lane>>4)*8 + jj,  t = tid>>6
        int L = b - 5;
        int lane = tid & 63;
        int t = tid >> 6;
        int j = lane & 15;
        int h = (j < 6) ? j : (j - 6);
        const float* att = (j < 6) ? fa.as[L] : fa.ad[L];
        const float* arow = att + h * D;
        f16x8 v;
        #pragma unroll
        for (int jj = 0; jj < 8; jj++) {
            int k = t * 32 + ((lane >> 4) << 3) + jj;
            float s = 0.f;
            if (j < 12) {
                const float* wrow = fa.W[L] + (size_t)k * K_ALL + h * D;
                #pragma unroll 8
                for (int c = 0; c < D; c++) s += wrow[c] * arow[c];
            }
            v[jj] = (_Float16)s;
        }
        *(f16x8*)(waf + (size_t)(L - 1) * 2048 + (size_t)t * 512 + (size_t)lane * 8) = v;
    } else {
        int idx = (b - 9) * 256 + tid;    // < 4*TSTEPS*8*64 = 49152
        int l63 = idx & 63;
        int ct = (idx >> 6) & 7;
        int t = (idx >> 9) % TSTEPS;
        int layer = idx / (TSTEPS * 8 * 64);
        const float* W = fa.W[layer];
        int c = ct * 16 + (l63 & 15);
        f16x8 v;
        #pragma unroll
        for (int j = 0; j < 8; j++) {
            int k = t * 32 + ((l63 >> 4) << 3) + j;
            v[j] = (_Float16)W[(size_t)(k & 127) * K_ALL + ((k >> 7) << 7) + c];
        }
        *(f16x8*)(bf + ((size_t)idx << 3)) = v;
    }
}

// a[n][j] = x[n,:] @ wa[:,j]   (one wave per node) — layer 0 only
__global__ __launch_bounds__(256) void compute_a_kernel(const float* __restrict__ x,
                                                        const float* __restrict__ wa,
                                                        float* __restrict__ a, int n_nodes) {
    __shared__ float swa[128 * 12];
    for (int i = threadIdx.x; i < 128 * 12; i += 256) swa[i] = wa[i];
    __syncthreads();
    int wid = (int)((blockIdx.x * blockDim.x + threadIdx.x) >> 6);
    int lane = threadIdx.x & 63;
    if (wid >= n_nodes) return;
    float x0 = x[(size_t)wid * D + lane];
    float x1 = x[(size_t)wid * D + 64 + lane];
    #pragma unroll
    for (int j = 0; j < 12; j++) {
        float p = x0 * swa[lane * 12 + j] + x1 * swa[(64 + lane) * 12 + j];
        #pragma unroll
        for (int off = 32; off; off >>= 1) p += __shfl_xor(p, off, 64);
        if (lane == 0) a[(size_t)wid * 12 + j] = p;
    }
}

__device__ __forceinline__ float rlf(float v, int j) {
    return __int_as_float(__builtin_amdgcn_readlane(__float_as_int(v), j));
}

// One wave per dst node; lane-parallel softmax; readlane-broadcast pipelined
// x-gather. Writes aggregation result directly as f16 MFMA A-fragments.
__global__ __launch_bounds__(256) void aggregate_kernel(const float* __restrict__ x,
                                                        const float* __restrict__ a,
                                                        const int* __restrict__ rowend,
                                                        const int* __restrict__ deg_,
                                                        const int* __restrict__ col,
                                                        __half* __restrict__ aggf, int n_nodes) {
    int wid = (int)((blockIdx.x * blockDim.x + threadIdx.x) >> 6);
    int lane = threadIdx.x & 63;
    if (wid >= n_nodes) return;
    const int n = wid;
    const int deg = deg_[n];
    const int start = rowend[n] - deg;
    const int nent = deg + 1;

    const int mt64 = n >> 6;
    const int rg = (n >> 4) & 3;
    const int rr = n & 15;

    float adst[H];
    #pragma unroll
    for (int h = 0; h < H; h++) adst[h] = a[(size_t)n * 12 + 6 + h];

    if (nent <= 64) {
        const bool act = lane < nent;
        int s = n;                          // lane 'deg' = self loop
        if (lane < deg) s = col[start + lane];

        const float* as_ = a + (size_t)s * 12;
        float4 v0 = *(const float4*)as_;
        float2 v1 = *(const float2*)(as_ + 4);
        float e0 = v0.x + adst[0], e1 = v0.y + adst[1], e2 = v0.z + adst[2];
        float e3 = v0.w + adst[3], e4 = v1.x + adst[4], e5 = v1.y + adst[5];
        e0 = e0 > 0.f ? e0 : 0.2f * e0;  e1 = e1 > 0.f ? e1 : 0.2f * e1;
        e2 = e2 > 0.f ? e2 : 0.2f * e2;  e3 = e3 > 0.f ? e3 : 0.2f * e3;
        e4 = e4 > 0.f ? e4 : 0.2f * e4;  e5 = e5 > 0.f ? e5 : 0.2f * e5;
        if (!act) { e0 = e1 = e2 = e3 = e4 = e5 = -1e30f; }

        float m0 = e0, m1 = e1, m2 = e2, m3 = e3, m4 = e4, m5 = e5;
        #pragma unroll
        for (int off = 32; off; off >>= 1) {
            m0 = fmaxf(m0, __shfl_xor(m0, off, 64));
            m1 = fmaxf(m1, __shfl_xor(m1, off, 64));
            m2 = fmaxf(m2, __shfl_xor(m2, off, 64));
            m3 = fmaxf(m3, __shfl_xor(m3, off, 64));
            m4 = fmaxf(m4, __shfl_xor(m4, off, 64));
            m5 = fmaxf(m5, __shfl_xor(m5, off, 64));
        }
        float w0 = act ? __expf(e0 - m0) : 0.f;
        float w1 = act ? __expf(e1 - m1) : 0.f;
        float w2 = act ? __expf(e2 - m2) : 0.f;
        float w3 = act ? __expf(e3 - m3) : 0.f;
        float w4 = act ? __expf(e4 - m4) : 0.f;
        float w5 = act ? __expf(e5 - m5) : 0.f;
        float d0 = w0, d1 = w1, d2 = w2, d3 = w3, d4 = w4, d5 = w5;
        #pragma unroll
        for (int off = 32; off; off >>= 1) {
            d0 += __shfl_xor(d0, off, 64);  d1 += __shfl_xor(d1, off, 64);
            d2 += __shfl_xor(d2, off, 64);  d3 += __shfl_xor(d3, off, 64);
            d4 += __shfl_xor(d4, off, 64);  d5 += __shfl_xor(d5, off, 64);
        }
        w0 *= 1.f / (d0 + 1e-16f);  w1 *= 1.f / (d1 + 1e-16f);
        w2 *= 1.f / (d2 + 1e-16f);  w3 *= 1.f / (d3 + 1e-16f);
        w4 *= 1.f / (d4 + 1e-16f);  w5 *= 1.f / (d5 + 1e-16f);

        float a00 = 0, a01 = 0, a02 = 0, a03 = 0, a04 = 0, a05 = 0;
        float a10 = 0, a11 = 0, a12 = 0, a13 = 0, a14 = 0, a15 = 0;
        const float* xb = x + (lane << 1);   // channels c=2*lane, 2*lane+1

        float2 xa, xbv;
        {
            int s0 = __builtin_amdgcn_readlane(s, 0);
            xa = *(const float2*)(xb + (size_t)s0 * D);
        }
        xbv = make_float2(0.f, 0.f);
        if (nent > 1) {
            int s1 = __builtin_amdgcn_readlane(s, 1);
            xbv = *(const float2*)(xb + (size_t)s1 * D);
        }
        for (int j = 0; j < nent; j += 2) {
            float2 xn0 = make_float2(0.f, 0.f), xn1 = make_float2(0.f, 0.f);
            if (j + 2 < nent) {
                int s2 = __builtin_amdgcn_readlane(s, j + 2);
                xn0 = *(const float2*)(xb + (size_t)s2 * D);
            }
            if (j + 3 < nent) {
                int s3 = __builtin_amdgcn_readlane(s, j + 3);
                xn1 = *(const float2*)(xb + (size_t)s3 * D);
            }
            {
                float b0 = rlf(w0, j), b1 = rlf(w1, j), b2 = rlf(w2, j);
                float b3 = rlf(w3, j), b4 = rlf(w4, j), b5 = rlf(w5, j);
                a00 += b0 * xa.x; a10 += b0 * xa.y;
                a01 += b1 * xa.x; a11 += b1 * xa.y;
                a02 += b2 * xa.x; a12 += b2 * xa.y;
                a03 += b3 * xa.x; a13 += b3 * xa.y;
                a04 += b4 * xa.x; a14 += b4 * xa.y;
                a05 += b5 * xa.x; a15 += b5 * xa.y;
            }
            if (j + 1 < nent) {
                float b0 = rlf(w0, j + 1), b1 = rlf(w1, j + 1), b2 = rlf(w2, j + 1);
                float b3 = rlf(w3, j + 1), b4 = rlf(w4, j + 1), b5 = rlf(w5, j + 1);
                a00 += b0 * xbv.x; a10 += b0 * xbv.y;
                a01 += b1 * xbv.x; a11 += b1 * xbv.y;
                a02 += b2 * xbv.x; a12 += b2 * xbv.y;
                a03 += b3 * xbv.x; a13 += b3 * xbv.y;
                a04 += b4 * xbv.x; a14 += b4 * xbv.y;
                a05 += b5 * xbv.x; a15 += b5 * xbv.y;
            }
            xa = xn0; xbv = xn1;
        }
        // fragment-order f16 writes: c=2*lane (+1) -> k=h*128+2*lane(+1)
        int g = (lane & 15) >> 2;
        int jj = (lane & 3) << 1;
        int lam = rr + (g << 4);
        int thi = lane >> 4;
        size_t base = (((size_t)mt64 * TSTEPS) * 4 + rg) * 512 + (size_t)lam * 8 + jj;
        *(__half2*)(aggf + base + (size_t)(0 * 4 + thi) * 2048) = __floats2half2_rn(a00, a10);
        *(__half2*)(aggf + base + (size_t)(1 * 4 + thi) * 2048) = __floats2half2_rn(a01, a11);
        *(__half2*)(aggf + base + (size_t)(2 * 4 + thi) * 2048) = __floats2half2_rn(a02, a12);
        *(__half2*)(aggf + base + (size_t)(3 * 4 + thi) * 2048) = __floats2half2_rn(a03, a13);
        *(__half2*)(aggf + base + (size_t)(4 * 4 + thi) * 2048) = __floats2half2_rn(a04, a14);
        *(__half2*)(aggf + base + (size_t)(5 * 4 + thi) * 2048) = __floats2half2_rn(a05, a15);
    } else {
        // slow fallback (deg >= 64): channels c0=lane, c1=64+lane
        float m[H];
        #pragma unroll
        for (int h = 0; h < H; h++) {
            float e = a[(size_t)n * 12 + h] + adst[h];
            m[h] = (e > 0.f) ? e : 0.2f * e;
        }
        for (int j = 0; j < deg; j++) {
            int s = col[start + j];
            #pragma unroll
            for (int h = 0; h < H; h++) {
                float e = a[(size_t)s * 12 + h] + adst[h];
                e = (e > 0.f) ? e : 0.2f * e;
                m[h] = fmaxf(m[h], e);
            }
        }
        float d[H] = {0, 0, 0, 0, 0, 0};
        float acc0[H] = {0, 0, 0, 0, 0, 0};
        float acc1[H] = {0, 0, 0, 0, 0, 0};
        int c0 = lane, c1 = 64 + lane;
        for (int j = 0; j <= deg; j++) {
            int s = (j < deg) ? col[start + j] : n;
            float w[H];
            #pragma unroll
            for (int h = 0; h < H; h++) {
                float e = a[(size_t)s * 12 + h] + adst[h];
                e = (e > 0.f) ? e : 0.2f * e;
                w[h] = __expf(e - m[h]);
                d[h] += w[h];
            }
            float xv0 = x[(size_t)s * D + c0];
            float xv1 = x[(size_t)s * D + c1];
            #pragma unroll
            for (int h = 0; h < H; h++) {
                acc0[h] += w[h] * xv0;
                acc1[h] += w[h] * xv1;
            }
        }
        int g = (lane & 31) >> 3;
        int jj = lane & 7;
        int lam = rr + (g << 4);
        int thi = lane >> 5;
        #pragma unroll
        for (int h = 0; h < H; h++) {
            float inv = 1.0f / (d[h] + 1e-16f);
            size_t i0 = (((size_t)mt64 * TSTEPS + (h * 4 + thi)) * 4 + rg) * 512 + (size_t)lam * 8 + jj;
            size_t i1 = (((size_t)mt64 * TSTEPS + (h * 4 + 2 + thi)) * 4 + rg) * 512 + (size_t)lam * 8 + jj;
            aggf[i0] = (_Float16)(acc0[h] * inv);
            aggf[i1] = (_Float16)(acc1[h] * inv);
        }
    }
}

// ---------------- MFMA GEMM + fused next-layer a ----------------
// out = relu(aggf @ B / 6 + bias); if awf: a[m][j] = out[m,:] @ wa (4 MFMAs, wave 0)
__global__ __launch_bounds__(256) void gemm_mfma_kernel(const __half* __restrict__ aggf,
                                                        const __half* __restrict__ bf,
                                                        const float* __restrict__ bias,
                                                        float* __restrict__ out,
                                                        const __half* __restrict__ awf,
                                                        float* __restrict__ a_out, int M) {
    __shared__ _Float16 xs[16][80];
    const int wave = (int)(threadIdx.x >> 6);
    const int lane = (int)(threadIdx.x & 63);
    const int mt64 = blockIdx.x >> 2;
    const int rg = blockIdx.x & 3;
    const int m0 = blockIdx.x << 4;

    f32x4 acc0 = {0.f, 0.f, 0.f, 0.f};
    f32x4 acc1 = {0.f, 0.f, 0.f, 0.f};

    const __half* ap = aggf + (((size_t)mt64 * TSTEPS) * 4 + rg) * 512 + (size_t)lane * 8;
    const __half* bp = bf + (size_t)(wave * 2) * 512 + (size_t)lane * 8;

    for (int t = 0; t < TSTEPS; t++) {
        f16x8 av = *(const f16x8*)(ap + (size_t)t * 2048);
        f16x8 bv0 = *(const f16x8*)(bp + (size_t)t * 4096);
        f16x8 bv1 = *(const f16x8*)(bp + (size_t)t * 4096 + 512);
        acc0 = __builtin_amdgcn_mfma_f32_16x16x32_f16(av, bv0, acc0, 0, 0, 0);
        acc1 = __builtin_amdgcn_mfma_f32_16x16x32_f16(av, bv1, acc1, 0, 0, 0);
    }

    const float inv6 = 1.0f / 6.0f;
    const int cl = lane & 15;
    const int c0 = wave * 32 + cl;
    const int r0 = (lane >> 4) << 2;
    const float b0 = bias[c0];
    const float b1 = bias[c0 + 16];
    #pragma unroll
    for (int reg = 0; reg < 4; reg++) {
        int ml = r0 + reg;
        int m = m0 + ml;
        float v0 = acc0[reg] * inv6 + b0;  v0 = v0 > 0.f ? v0 : 0.f;
        float v1 = acc1[reg] * inv6 + b1;  v1 = v1 > 0.f ? v1 : 0.f;
        if (m < M) {
            out[(size_t)m * D + c0] = v0;
            out[(size_t)m * D + c0 + 16] = v1;
        } else { v0 = 0.f; v1 = 0.f; }
        xs[ml][c0] = (_Float16)v0;
        xs[ml][c0 + 16] = (_Float16)v1;
    }

    if (awf) {
        __syncthreads();
        if (wave == 0) {
            f32x4 ac = {0.f, 0.f, 0.f, 0.f};
            #pragma unroll
            for (int t = 0; t < 4; t++) {
                f16x8 av = *(const f16x8*)&xs[cl][t * 32 + ((lane >> 4) << 3)];
                f16x8 bv = *(const f16x8*)(awf + (size_t)t * 512 + (size_t)lane * 8);
                ac = __builtin_amdgcn_mfma_f32_16x16x32_f16(av, bv, ac, 0, 0, 0);
            }
            if (cl < 12) {
                #pragma unroll
                for (int reg = 0; reg < 4; reg++) {
                    int m = m0 + r0 + reg;
                    if (m < M) a_out[(size_t)m * 12 + cl] = ac[reg];
                }
            }
        }
    }
}

// ---------------- host ----------------

extern "C" void kernel_launch(void* const* d_in, const int* in_sizes, int n_in,
                              void* d_out, int out_size, void* d_ws, size_t ws_size,
                              hipStream_t stream) {
    const float* x_in = (const float*)d_in[0];
    const int* ei = (const int*)d_in[1];
    int N = in_sizes[0] / D;
    int E = in_sizes[1] / 2;
    const int* srcp = ei;
    const int* dstp = ei + E;

    int nt64 = (N + 63) >> 6;
    size_t aggf_halves = (size_t)nt64 * TSTEPS * 4 * 512;
    size_t bf_halves_per_layer = (size_t)TSTEPS * 8 * 512;

    float* ws = (float*)d_ws;
    float* bufA = ws;
    float* bufB = bufA + (size_t)N * D;
    float* abuf = bufB + (size_t)N * D;
    float* wa0 = abuf + (size_t)N * 12;
    __half* waf = (__half*)(wa0 + 1536);          // 3 layers x 2048 halves
    __half* aggf = waf + 3 * 2048;
    __half* w16f = aggf + aggf_halves;
    int* deg = (int*)(w16f + 4 * bf_halves_per_layer);
    int* rowptr = deg + N;
    int* col = rowptr + (N + 1);

    // CSR build
    hipMemsetAsync(deg, 0, (size_t)N * sizeof(int), stream);
    hist_kernel<<<(E + 255) / 256, 256, 0, stream>>>(dstp, deg, E);
    scan_kernel<<<1, 1024, 0, stream>>>(deg, rowptr, N);
    scatter_kernel<<<(E + 255) / 256, 256, 0, stream>>>(srcp, dstp, rowptr, col, E);

    // one-time weight prep (merged)
    FoldArgs fa;
    for (int l = 0; l < 4; l++) {
        fa.W[l]  = (const float*)d_in[2 + 4 * l];
        fa.as[l] = (const float*)d_in[3 + 4 * l];
        fa.ad[l] = (const float*)d_in[4 + 4 * l];
    }
    prep_kernel<<<201, 256, 0, stream>>>(fa, wa0, waf, w16f);

    // layer 0 attention logits
    compute_a_kernel<<<(N + 3) / 4, 256, 0, stream>>>(x_in, wa0, abuf, N);

    const float* xcur = x_in;
    for (int l = 0; l < 4; l++) {
        const float* b = (const float*)d_in[5 + 4 * l];
        float* xout = (l == 3) ? (float*)d_out : ((l & 1) ? bufB : bufA);
        const __half* awf = (l < 3) ? (waf + (size_t)l * 2048) : (const __half*)nullptr;

        aggregate_kernel<<<(N + 3) / 4, 256, 0, stream>>>(xcur, abuf, rowptr, deg, col, aggf, N);
        gemm_mfma_kernel<<<(N + 15) / 16, 256, 0, stream>>>(aggf,
                                                            w16f + (size_t)l * bf_halves_per_layer,
                                                            b, xout, awf, abuf, N);
        xcur = xout;
    }
}

// Round 8
// 199.064 us; speedup vs baseline: 47.0708x; 1.2092x over previous
//
#include <hip/hip_runtime.h>
#include <hip/hip_fp16.h>
#include <math.h>

#define H 6
#define D 128
#define K_ALL (H * D)   // 768
#define TSTEPS 24       // K_ALL / 32

typedef _Float16 f16x8 __attribute__((ext_vector_type(8)));
typedef float f32x4 __attribute__((ext_vector_type(4)));

struct FoldArgs {
    const float* W[4];
    const float* as[4];
    const float* ad[4];
};

// ---------------- CSR build + fused prep ----------------

// blocks [0, histBlocks): histogram. blocks [histBlocks, +24): wa_all dots.
__global__ __launch_bounds__(256) void hist_prep1_kernel(const int* __restrict__ dst,
                                                         int* __restrict__ deg, int E,
                                                         int histBlocks, FoldArgs fa,
                                                         float* __restrict__ wa_all) {
    int b = blockIdx.x;
    int tid = threadIdx.x;
    if (b < histBlocks) {
        int e = b * 256 + tid;
        if (e < E) atomicAdd(&deg[dst[e]], 1);
    } else {
        int t = (b - histBlocks) * 256 + tid;   // < 6144
        if (t >= 4 * 1536) return;
        int l = t / 1536;
        int r = t % 1536;
        int k = r / 12, j = r % 12;
        int h = (j < 6) ? j : (j - 6);
        const float* att = (j < 6) ? fa.as[l] : fa.ad[l];
        const float* wrow = fa.W[l] + (size_t)k * K_ALL + h * D;
        const float* arow = att + h * D;
        float s = 0.f;
        #pragma unroll 8
        for (int c = 0; c < D; c++) s += wrow[c] * arow[c];
        wa_all[(size_t)l * 1536 + k * 12 + j] = s;
    }
}

// single-pass scan: thread i owns elements [i*16, i*16+16); 2 barriers total.
__global__ __launch_bounds__(1024) void scan_kernel(const int* __restrict__ deg,
                                                    int* __restrict__ rowptr, int n) {
    __shared__ int wsum[16];
    const int tid = threadIdx.x;
    const int lane = tid & 63;
    const int wv = tid >> 6;
    const int base = tid << 4;

    int v[16];
    int tot = 0;
    #pragma unroll
    for (int k = 0; k < 16; k++) {
        int i = base + k;
        int d = (i < n) ? deg[i] : 0;
        v[k] = tot;
        tot += d;
    }
    int s = tot;
    #pragma unroll
    for (int off = 1; off < 64; off <<= 1) {
        int t = __shfl_up(s, off, 64);
        if (lane >= off) s += t;
    }
    if (lane == 63) wsum[wv] = s;
    __syncthreads();
    if (tid < 16) {
        int t = wsum[tid];
        #pragma unroll
        for (int off = 1; off < 16; off <<= 1) {
            int u = __shfl_up(t, off, 64);
            if ((int)tid >= off) t += u;
        }
        wsum[tid] = t;
    }
    __syncthreads();
    int off0 = ((wv > 0) ? wsum[wv - 1] : 0) + s - tot;
    #pragma unroll
    for (int k = 0; k < 16; k++) {
        int i = base + k;
        if (i < n) rowptr[i] = off0 + v[k];
    }
}

// blocks [0, scatBlocks): scatter. +[0,3): waf pack (from wa_all). +[3,195): bf pack.
__global__ __launch_bounds__(256) void scatter_prep2_kernel(const int* __restrict__ src,
                                                            const int* __restrict__ dst,
                                                            int* __restrict__ rowcur,
                                                            int* __restrict__ col, int E,
                                                            int scatBlocks, FoldArgs fa,
                                                            const float* __restrict__ wa_all,
                                                            __half* __restrict__ waf,
                                                            __half* __restrict__ bf) {
    int b = blockIdx.x;
    int tid = threadIdx.x;
    if (b < scatBlocks) {
        int e = b * 256 + tid;
        if (e < E) {
            int p = atomicAdd(&rowcur[dst[e]], 1);
            col[p] = src[e];
        }
        return;
    }
    int bb = b - scatBlocks;
    if (bb < 3) {
        // waf for layer L = bb+1: frag value = wa_L[k][j], j = lane&15 (<12 else 0),
        // k = t*32 + (lane>>4)*8 + jj, t = tid>>6 (0..3)
        int L = bb + 1;
        int lane = tid & 63;
        int t = tid >> 6;
        int j = lane & 15;
        const float* wl = wa_all + (size_t)L * 1536;
        f16x8 v;
        #pragma unroll
        for (int jj = 0; jj < 8; jj++) {
            int k = t * 32 + ((lane >> 4) << 3) + jj;
            float s = (j < 12) ? wl[k * 12 + j] : 0.f;
            v[jj] = (_Float16)s;
        }
        *(f16x8*)(waf + (size_t)bb * 2048 + (size_t)t * 512 + (size_t)lane * 8) = v;
    } else {
        int idx = (bb - 3) * 256 + tid;    // < 4*TSTEPS*8*64 = 49152
        int l63 = idx & 63;
        int ct = (idx >> 6) & 7;
        int t = (idx >> 9) % TSTEPS;
        int layer = idx / (TSTEPS * 8 * 64);
        const float* W = fa.W[layer];
        int c = ct * 16 + (l63 & 15);
        f16x8 v;
        #pragma unroll
        for (int j = 0; j < 8; j++) {
            int k = t * 32 + ((l63 >> 4) << 3) + j;
            v[j] = (_Float16)W[(size_t)(k & 127) * K_ALL + ((k >> 7) << 7) + c];
        }
        *(f16x8*)(bf + ((size_t)idx << 3)) = v;
    }
}

// a[n][j] = x[n,:] @ wa[:,j]   (one wave per node) — layer 0 only
__global__ __launch_bounds__(256) void compute_a_kernel(const float* __restrict__ x,
                                                        const float* __restrict__ wa,
                                                        float* __restrict__ a, int n_nodes) {
    __shared__ float swa[128 * 12];
    for (int i = threadIdx.x; i < 128 * 12; i += 256) swa[i] = wa[i];
    __syncthreads();
    int wid = (int)((blockIdx.x * blockDim.x + threadIdx.x) >> 6);
    int lane = threadIdx.x & 63;
    if (wid >= n_nodes) return;
    float x0 = x[(size_t)wid * D + lane];
    float x1 = x[(size_t)wid * D + 64 + lane];
    #pragma unroll
    for (int j = 0; j < 12; j++) {
        float p = x0 * swa[lane * 12 + j] + x1 * swa[(64 + lane) * 12 + j];
        #pragma unroll
        for (int off = 32; off; off >>= 1) p += __shfl_xor(p, off, 64);
        if (lane == 0) a[(size_t)wid * 12 + j] = p;
    }
}

__device__ __forceinline__ float rlf(float v, int j) {
    return __int_as_float(__builtin_amdgcn_readlane(__float_as_int(v), j));
}

// One wave per dst node; lane-parallel softmax; readlane-broadcast pipelined
// x-gather. Writes aggregation result directly as f16 MFMA A-fragments.
__global__ __launch_bounds__(256) void aggregate_kernel(const float* __restrict__ x,
                                                        const float* __restrict__ a,
                                                        const int* __restrict__ rowend,
                                                        const int* __restrict__ deg_,
                                                        const int* __restrict__ col,
                                                        __half* __restrict__ aggf, int n_nodes) {
    int wid = (int)((blockIdx.x * blockDim.x + threadIdx.x) >> 6);
    int lane = threadIdx.x & 63;
    if (wid >= n_nodes) return;
    const int n = wid;
    const int deg = deg_[n];
    const int start = rowend[n] - deg;
    const int nent = deg + 1;

    const int mt64 = n >> 6;
    const int rg = (n >> 4) & 3;
    const int rr = n & 15;

    float adst[H];
    #pragma unroll
    for (int h = 0; h < H; h++) adst[h] = a[(size_t)n * 12 + 6 + h];

    if (nent <= 64) {
        const bool act = lane < nent;
        int s = n;                          // lane 'deg' = self loop
        if (lane < deg) s = col[start + lane];

        const float* as_ = a + (size_t)s * 12;
        float4 v0 = *(const float4*)as_;
        float2 v1 = *(const float2*)(as_ + 4);
        float e0 = v0.x + adst[0], e1 = v0.y + adst[1], e2 = v0.z + adst[2];
        float e3 = v0.w + adst[3], e4 = v1.x + adst[4], e5 = v1.y + adst[5];
        e0 = e0 > 0.f ? e0 : 0.2f * e0;  e1 = e1 > 0.f ? e1 : 0.2f * e1;
        e2 = e2 > 0.f ? e2 : 0.2f * e2;  e3 = e3 > 0.f ? e3 : 0.2f * e3;
        e4 = e4 > 0.f ? e4 : 0.2f * e4;  e5 = e5 > 0.f ? e5 : 0.2f * e5;
        if (!act) { e0 = e1 = e2 = e3 = e4 = e5 = -1e30f; }

        float m0 = e0, m1 = e1, m2 = e2, m3 = e3, m4 = e4, m5 = e5;
        #pragma unroll
        for (int off = 32; off; off >>= 1) {
            m0 = fmaxf(m0, __shfl_xor(m0, off, 64));
            m1 = fmaxf(m1, __shfl_xor(m1, off, 64));
            m2 = fmaxf(m2, __shfl_xor(m2, off, 64));
            m3 = fmaxf(m3, __shfl_xor(m3, off, 64));
            m4 = fmaxf(m4, __shfl_xor(m4, off, 64));
            m5 = fmaxf(m5, __shfl_xor(m5, off, 64));
        }
        float w0 = act ? __expf(e0 - m0) : 0.f;
        float w1 = act ? __expf(e1 - m1) : 0.f;
        float w2 = act ? __expf(e2 - m2) : 0.f;
        float w3 = act ? __expf(e3 - m3) : 0.f;
        float w4 = act ? __expf(e4 - m4) : 0.f;
        float w5 = act ? __expf(e5 - m5) : 0.f;
        float d0 = w0, d1 = w1, d2 = w2, d3 = w3, d4 = w4, d5 = w5;
        #pragma unroll
        for (int off = 32; off; off >>= 1) {
            d0 += __shfl_xor(d0, off, 64);  d1 += __shfl_xor(d1, off, 64);
            d2 += __shfl_xor(d2, off, 64);  d3 += __shfl_xor(d3, off, 64);
            d4 += __shfl_xor(d4, off, 64);  d5 += __shfl_xor(d5, off, 64);
        }
        w0 *= 1.f / (d0 + 1e-16f);  w1 *= 1.f / (d1 + 1e-16f);
        w2 *= 1.f / (d2 + 1e-16f);  w3 *= 1.f / (d3 + 1e-16f);
        w4 *= 1.f / (d4 + 1e-16f);  w5 *= 1.f / (d5 + 1e-16f);

        float a00 = 0, a01 = 0, a02 = 0, a03 = 0, a04 = 0, a05 = 0;
        float a10 = 0, a11 = 0, a12 = 0, a13 = 0, a14 = 0, a15 = 0;
        const float* xb = x + (lane << 1);   // channels c=2*lane, 2*lane+1

        float2 xa, xbv;
        {
            int s0 = __builtin_amdgcn_readlane(s, 0);
            xa = *(const float2*)(xb + (size_t)s0 * D);
        }
        xbv = make_float2(0.f, 0.f);
        if (nent > 1) {
            int s1 = __builtin_amdgcn_readlane(s, 1);
            xbv = *(const float2*)(xb + (size_t)s1 * D);
        }
        for (int j = 0; j < nent; j += 2) {
            float2 xn0 = make_float2(0.f, 0.f), xn1 = make_float2(0.f, 0.f);
            if (j + 2 < nent) {
                int s2 = __builtin_amdgcn_readlane(s, j + 2);
                xn0 = *(const float2*)(xb + (size_t)s2 * D);
            }
            if (j + 3 < nent) {
                int s3 = __builtin_amdgcn_readlane(s, j + 3);
                xn1 = *(const float2*)(xb + (size_t)s3 * D);
            }
            {
                float b0 = rlf(w0, j), b1 = rlf(w1, j), b2 = rlf(w2, j);
                float b3 = rlf(w3, j), b4 = rlf(w4, j), b5 = rlf(w5, j);
                a00 += b0 * xa.x; a10 += b0 * xa.y;
                a01 += b1 * xa.x; a11 += b1 * xa.y;
                a02 += b2 * xa.x; a12 += b2 * xa.y;
                a03 += b3 * xa.x; a13 += b3 * xa.y;
                a04 += b4 * xa.x; a14 += b4 * xa.y;
                a05 += b5 * xa.x; a15 += b5 * xa.y;
            }
            if (j + 1 < nent) {
                float b0 = rlf(w0, j + 1), b1 = rlf(w1, j + 1), b2 = rlf(w2, j + 1);
                float b3 = rlf(w3, j + 1), b4 = rlf(w4, j + 1), b5 = rlf(w5, j + 1);
                a00 += b0 * xbv.x; a10 += b0 * xbv.y;
                a01 += b1 * xbv.x; a11 += b1 * xbv.y;
                a02 += b2 * xbv.x; a12 += b2 * xbv.y;
                a03 += b3 * xbv.x; a13 += b3 * xbv.y;
                a04 += b4 * xbv.x; a14 += b4 * xbv.y;
                a05 += b5 * xbv.x; a15 += b5 * xbv.y;
            }
            xa = xn0; xbv = xn1;
        }
        // fragment-order f16 writes: c=2*lane (+1) -> k=h*128+2*lane(+1)
        int g = (lane & 15) >> 2;
        int jj = (lane & 3) << 1;
        int lam = rr + (g << 4);
        int thi = lane >> 4;
        size_t base = (((size_t)mt64 * TSTEPS) * 4 + rg) * 512 + (size_t)lam * 8 + jj;
        *(__half2*)(aggf + base + (size_t)(0 * 4 + thi) * 2048) = __floats2half2_rn(a00, a10);
        *(__half2*)(aggf + base + (size_t)(1 * 4 + thi) * 2048) = __floats2half2_rn(a01, a11);
        *(__half2*)(aggf + base + (size_t)(2 * 4 + thi) * 2048) = __floats2half2_rn(a02, a12);
        *(__half2*)(aggf + base + (size_t)(3 * 4 + thi) * 2048) = __floats2half2_rn(a03, a13);
        *(__half2*)(aggf + base + (size_t)(4 * 4 + thi) * 2048) = __floats2half2_rn(a04, a14);
        *(__half2*)(aggf + base + (size_t)(5 * 4 + thi) * 2048) = __floats2half2_rn(a05, a15);
    } else {
        // slow fallback (deg >= 64): channels c0=lane, c1=64+lane
        float m[H];
        #pragma unroll
        for (int h = 0; h < H; h++) {
            float e = a[(size_t)n * 12 + h] + adst[h];
            m[h] = (e > 0.f) ? e : 0.2f * e;
        }
        for (int j = 0; j < deg; j++) {
            int s = col[start + j];
            #pragma unroll
            for (int h = 0; h < H; h++) {
                float e = a[(size_t)s * 12 + h] + adst[h];
                e = (e > 0.f) ? e : 0.2f * e;
                m[h] = fmaxf(m[h], e);
            }
        }
        float d[H] = {0, 0, 0, 0, 0, 0};
        float acc0[H] = {0, 0, 0, 0, 0, 0};
        float acc1[H] = {0, 0, 0, 0, 0, 0};
        int c0 = lane, c1 = 64 + lane;
        for (int j = 0; j <= deg; j++) {
            int s = (j < deg) ? col[start + j] : n;
            float w[H];
            #pragma unroll
            for (int h = 0; h < H; h++) {
                float e = a[(size_t)s * 12 + h] + adst[h];
                e = (e > 0.f) ? e : 0.2f * e;
                w[h] = __expf(e - m[h]);
                d[h] += w[h];
            }
            float xv0 = x[(size_t)s * D + c0];
            float xv1 = x[(size_t)s * D + c1];
            #pragma unroll
            for (int h = 0; h < H; h++) {
                acc0[h] += w[h] * xv0;
                acc1[h] += w[h] * xv1;
            }
        }
        int g = (lane & 31) >> 3;
        int jj = lane & 7;
        int lam = rr + (g << 4);
        int thi = lane >> 5;
        #pragma unroll
        for (int h = 0; h < H; h++) {
            float inv = 1.0f / (d[h] + 1e-16f);
            size_t i0 = (((size_t)mt64 * TSTEPS + (h * 4 + thi)) * 4 + rg) * 512 + (size_t)lam * 8 + jj;
            size_t i1 = (((size_t)mt64 * TSTEPS + (h * 4 + 2 + thi)) * 4 + rg) * 512 + (size_t)lam * 8 + jj;
            aggf[i0] = (_Float16)(acc0[h] * inv);
            aggf[i1] = (_Float16)(acc1[h] * inv);
        }
    }
}

// ---------------- MFMA GEMM + fused next-layer a ----------------
// out = relu(aggf @ B / 6 + bias); if awf: a[m][j] = out[m,:] @ wa (4 MFMAs, wave 0)
__global__ __launch_bounds__(256) void gemm_mfma_kernel(const __half* __restrict__ aggf,
                                                        const __half* __restrict__ bf,
                                                        const float* __restrict__ bias,
                                                        float* __restrict__ out,
                                                        const __half* __restrict__ awf,
                                                        float* __restrict__ a_out, int M) {
    __shared__ _Float16 xs[16][80];
    const int wave = (int)(threadIdx.x >> 6);
    const int lane = (int)(threadIdx.x & 63);
    const int mt64 = blockIdx.x >> 2;
    const int rg = blockIdx.x & 3;
    const int m0 = blockIdx.x << 4;

    f32x4 acc0 = {0.f, 0.f, 0.f, 0.f};
    f32x4 acc1 = {0.f, 0.f, 0.f, 0.f};

    const __half* ap = aggf + (((size_t)mt64 * TSTEPS) * 4 + rg) * 512 + (size_t)lane * 8;
    const __half* bp = bf + (size_t)(wave * 2) * 512 + (size_t)lane * 8;

    for (int t = 0; t < TSTEPS; t++) {
        f16x8 av = *(const f16x8*)(ap + (size_t)t * 2048);
        f16x8 bv0 = *(const f16x8*)(bp + (size_t)t * 4096);
        f16x8 bv1 = *(const f16x8*)(bp + (size_t)t * 4096 + 512);
        acc0 = __builtin_amdgcn_mfma_f32_16x16x32_f16(av, bv0, acc0, 0, 0, 0);
        acc1 = __builtin_amdgcn_mfma_f32_16x16x32_f16(av, bv1, acc1, 0, 0, 0);
    }

    const float inv6 = 1.0f / 6.0f;
    const int cl = lane & 15;
    const int c0 = wave * 32 + cl;
    const int r0 = (lane >> 4) << 2;
    const float b0 = bias[c0];
    const float b1 = bias[c0 + 16];
    #pragma unroll
    for (int reg = 0; reg < 4; reg++) {
        int ml = r0 + reg;
        int m = m0 + ml;
        float v0 = acc0[reg] * inv6 + b0;  v0 = v0 > 0.f ? v0 : 0.f;
        float v1 = acc1[reg] * inv6 + b1;  v1 = v1 > 0.f ? v1 : 0.f;
        if (m < M) {
            out[(size_t)m * D + c0] = v0;
            out[(size_t)m * D + c0 + 16] = v1;
        } else { v0 = 0.f; v1 = 0.f; }
        xs[ml][c0] = (_Float16)v0;
        xs[ml][c0 + 16] = (_Float16)v1;
    }

    if (awf) {
        __syncthreads();
        if (wave == 0) {
            f32x4 ac = {0.f, 0.f, 0.f, 0.f};
            #pragma unroll
            for (int t = 0; t < 4; t++) {
                f16x8 av = *(const f16x8*)&xs[cl][t * 32 + ((lane >> 4) << 3)];
                f16x8 bv = *(const f16x8*)(awf + (size_t)t * 512 + (size_t)lane * 8);
                ac = __builtin_amdgcn_mfma_f32_16x16x32_f16(av, bv, ac, 0, 0, 0);
            }
            if (cl < 12) {
                #pragma unroll
                for (int reg = 0; reg < 4; reg++) {
                    int m = m0 + r0 + reg;
                    if (m < M) a_out[(size_t)m * 12 + cl] = ac[reg];
                }
            }
        }
    }
}

// ---------------- host ----------------

extern "C" void kernel_launch(void* const* d_in, const int* in_sizes, int n_in,
                              void* d_out, int out_size, void* d_ws, size_t ws_size,
                              hipStream_t stream) {
    const float* x_in = (const float*)d_in[0];
    const int* ei = (const int*)d_in[1];
    int N = in_sizes[0] / D;
    int E = in_sizes[1] / 2;
    const int* srcp = ei;
    const int* dstp = ei + E;

    int nt64 = (N + 63) >> 6;
    size_t aggf_halves = (size_t)nt64 * TSTEPS * 4 * 512;
    size_t bf_halves_per_layer = (size_t)TSTEPS * 8 * 512;

    float* ws = (float*)d_ws;
    float* bufA = ws;
    float* bufB = bufA + (size_t)N * D;
    float* abuf = bufB + (size_t)N * D;
    float* wa_all = abuf + (size_t)N * 12;        // 4*1536 floats
    __half* waf = (__half*)(wa_all + 4 * 1536);   // 3 layers x 2048 halves
    __half* aggf = waf + 3 * 2048;
    __half* w16f = aggf + aggf_halves;
    int* deg = (int*)(w16f + 4 * bf_halves_per_layer);
    int* rowptr = deg + N;
    int* col = rowptr + (N + 1);

    FoldArgs fa;
    for (int l = 0; l < 4; l++) {
        fa.W[l]  = (const float*)d_in[2 + 4 * l];
        fa.as[l] = (const float*)d_in[3 + 4 * l];
        fa.ad[l] = (const float*)d_in[4 + 4 * l];
    }

    // CSR build + fused prep
    hipMemsetAsync(deg, 0, (size_t)N * sizeof(int), stream);
    int histBlocks = (E + 255) / 256;
    hist_prep1_kernel<<<histBlocks + 24, 256, 0, stream>>>(dstp, deg, E, histBlocks, fa, wa_all);
    scan_kernel<<<1, 1024, 0, stream>>>(deg, rowptr, N);
    int scatBlocks = (E + 255) / 256;
    scatter_prep2_kernel<<<scatBlocks + 3 + 192, 256, 0, stream>>>(srcp, dstp, rowptr, col, E,
                                                                   scatBlocks, fa, wa_all,
                                                                   waf, w16f);

    // layer 0 attention logits
    compute_a_kernel<<<(N + 3) / 4, 256, 0, stream>>>(x_in, wa_all, abuf, N);

    const float* xcur = x_in;
    for (int l = 0; l < 4; l++) {
        const float* b = (const float*)d_in[5 + 4 * l];
        float* xout = (l == 3) ? (float*)d_out : ((l & 1) ? bufB : bufA);
        const __half* awf = (l < 3) ? (waf + (size_t)l * 2048) : (const __half*)nullptr;

        aggregate_kernel<<<(N + 3) / 4, 256, 0, stream>>>(xcur, abuf, rowptr, deg, col, aggf, N);
        gemm_mfma_kernel<<<(N + 15) / 16, 256, 0, stream>>>(aggf,
                                                            w16f + (size_t)l * bf_halves_per_layer,
                                                            b, xout, awf, abuf, N);
        xcur = xout;
    }
}

// Round 9
// 180.646 us; speedup vs baseline: 51.8698x; 1.1020x over previous
//
#include <hip/hip_runtime.h>
#include <hip/hip_fp16.h>
#include <math.h>

#define H 6
#define D 128
#define K_ALL (H * D)   // 768
#define TSTEPS 24       // K_ALL / 32
#define PADK 776        // 768 + 8 halves pad -> conflict-free fragment reads

typedef _Float16 f16x8 __attribute__((ext_vector_type(8)));
typedef float f32x4 __attribute__((ext_vector_type(4)));

struct FoldArgs {
    const float* W[4];
    const float* as[4];
    const float* ad[4];
};

// ---------------- CSR build + fused prep ----------------

// blocks [0, histBlocks): histogram. blocks [histBlocks, +24): wa_all dots.
__global__ __launch_bounds__(256) void hist_prep1_kernel(const int* __restrict__ dst,
                                                         int* __restrict__ deg, int E,
                                                         int histBlocks, FoldArgs fa,
                                                         float* __restrict__ wa_all) {
    int b = blockIdx.x;
    int tid = threadIdx.x;
    if (b < histBlocks) {
        int e = b * 256 + tid;
        if (e < E) atomicAdd(&deg[dst[e]], 1);
    } else {
        int t = (b - histBlocks) * 256 + tid;   // < 6144
        if (t >= 4 * 1536) return;
        int l = t / 1536;
        int r = t % 1536;
        int k = r / 12, j = r % 12;
        int h = (j < 6) ? j : (j - 6);
        const float* att = (j < 6) ? fa.as[l] : fa.ad[l];
        const float* wrow = fa.W[l] + (size_t)k * K_ALL + h * D;
        const float* arow = att + h * D;
        float s = 0.f;
        #pragma unroll 8
        for (int c = 0; c < D; c++) s += wrow[c] * arow[c];
        wa_all[(size_t)l * 1536 + k * 12 + j] = s;
    }
}

// single-pass scan: thread i owns elements [i*16, i*16+16); 2 barriers total.
__global__ __launch_bounds__(1024) void scan_kernel(const int* __restrict__ deg,
                                                    int* __restrict__ rowptr, int n) {
    __shared__ int wsum[16];
    const int tid = threadIdx.x;
    const int lane = tid & 63;
    const int wv = tid >> 6;
    const int base = tid << 4;

    int v[16];
    int tot = 0;
    #pragma unroll
    for (int k = 0; k < 16; k++) {
        int i = base + k;
        int d = (i < n) ? deg[i] : 0;
        v[k] = tot;
        tot += d;
    }
    int s = tot;
    #pragma unroll
    for (int off = 1; off < 64; off <<= 1) {
        int t = __shfl_up(s, off, 64);
        if (lane >= off) s += t;
    }
    if (lane == 63) wsum[wv] = s;
    __syncthreads();
    if (tid < 16) {
        int t = wsum[tid];
        #pragma unroll
        for (int off = 1; off < 16; off <<= 1) {
            int u = __shfl_up(t, off, 64);
            if ((int)tid >= off) t += u;
        }
        wsum[tid] = t;
    }
    __syncthreads();
    int off0 = ((wv > 0) ? wsum[wv - 1] : 0) + s - tot;
    #pragma unroll
    for (int k = 0; k < 16; k++) {
        int i = base + k;
        if (i < n) rowptr[i] = off0 + v[k];
    }
}

// blocks: [0,scat): scatter | +3: waf pack | +192: bf pack | +caBlocks: layer-0 a
__global__ __launch_bounds__(256) void scatter_prep2_kernel(const int* __restrict__ src,
                                                            const int* __restrict__ dst,
                                                            int* __restrict__ rowcur,
                                                            int* __restrict__ col, int E,
                                                            int scatBlocks, FoldArgs fa,
                                                            const float* __restrict__ wa_all,
                                                            __half* __restrict__ waf,
                                                            __half* __restrict__ bf,
                                                            const float* __restrict__ x_in,
                                                            float* __restrict__ a0, int N) {
    __shared__ float swa[1536];
    int b = blockIdx.x;
    int tid = threadIdx.x;
    if (b < scatBlocks) {
        int e = b * 256 + tid;
        if (e < E) {
            int p = atomicAdd(&rowcur[dst[e]], 1);
            col[p] = src[e];
        }
        return;
    }
    int bb = b - scatBlocks;
    if (bb < 3) {
        // waf for layer L = bb+1
        int L = bb + 1;
        int lane = tid & 63;
        int t = tid >> 6;
        int j = lane & 15;
        const float* wl = wa_all + (size_t)L * 1536;
        f16x8 v;
        #pragma unroll
        for (int jj = 0; jj < 8; jj++) {
            int k = t * 32 + ((lane >> 4) << 3) + jj;
            float s = (j < 12) ? wl[k * 12 + j] : 0.f;
            v[jj] = (_Float16)s;
        }
        *(f16x8*)(waf + (size_t)bb * 2048 + (size_t)t * 512 + (size_t)lane * 8) = v;
        return;
    }
    bb -= 3;
    if (bb < 192) {
        int idx = bb * 256 + tid;    // < 49152
        int l63 = idx & 63;
        int ct = (idx >> 6) & 7;
        int t = (idx >> 9) % TSTEPS;
        int layer = idx / (TSTEPS * 8 * 64);
        const float* W = fa.W[layer];
        int c = ct * 16 + (l63 & 15);
        f16x8 v;
        #pragma unroll
        for (int j = 0; j < 8; j++) {
            int k = t * 32 + ((l63 >> 4) << 3) + j;
            v[j] = (_Float16)W[(size_t)(k & 127) * K_ALL + ((k >> 7) << 7) + c];
        }
        *(f16x8*)(bf + ((size_t)idx << 3)) = v;
        return;
    }
    bb -= 192;
    // layer-0 a: one wave per node
    for (int i = tid; i < 1536; i += 256) swa[i] = wa_all[i];
    __syncthreads();
    int lane = tid & 63;
    int wid = bb * 4 + (tid >> 6);
    if (wid >= N) return;
    float x0 = x_in[(size_t)wid * D + lane];
    float x1 = x_in[(size_t)wid * D + 64 + lane];
    #pragma unroll
    for (int j = 0; j < 12; j++) {
        float p = x0 * swa[lane * 12 + j] + x1 * swa[(64 + lane) * 12 + j];
        #pragma unroll
        for (int off = 32; off; off >>= 1) p += __shfl_xor(p, off, 64);
        if (lane == 0) a0[(size_t)wid * 12 + j] = p;
    }
}

__device__ __forceinline__ float rlf(float v, int j) {
    return __int_as_float(__builtin_amdgcn_readlane(__float_as_int(v), j));
}

// per-wave: aggregate node n (softmax over incoming edges + self loop),
// write normalized result as f16 PLAIN layout into LDS row xsrow[0..767].
__device__ __forceinline__ void aggregate_node(const float* __restrict__ x,
                                               const float* __restrict__ a,
                                               const int* __restrict__ rowend,
                                               const int* __restrict__ deg_,
                                               const int* __restrict__ col,
                                               int n, int lane,
                                               _Float16* __restrict__ xsrow) {
    const int deg = deg_[n];
    const int start = rowend[n] - deg;
    const int nent = deg + 1;

    float adst[H];
    #pragma unroll
    for (int h = 0; h < H; h++) adst[h] = a[(size_t)n * 12 + 6 + h];

    if (nent <= 64) {
        const bool act = lane < nent;
        int s = n;                          // lane 'deg' = self loop
        if (lane < deg) s = col[start + lane];

        const float* as_ = a + (size_t)s * 12;
        float4 v0 = *(const float4*)as_;
        float2 v1 = *(const float2*)(as_ + 4);
        float e0 = v0.x + adst[0], e1 = v0.y + adst[1], e2 = v0.z + adst[2];
        float e3 = v0.w + adst[3], e4 = v1.x + adst[4], e5 = v1.y + adst[5];
        e0 = e0 > 0.f ? e0 : 0.2f * e0;  e1 = e1 > 0.f ? e1 : 0.2f * e1;
        e2 = e2 > 0.f ? e2 : 0.2f * e2;  e3 = e3 > 0.f ? e3 : 0.2f * e3;
        e4 = e4 > 0.f ? e4 : 0.2f * e4;  e5 = e5 > 0.f ? e5 : 0.2f * e5;
        if (!act) { e0 = e1 = e2 = e3 = e4 = e5 = -1e30f; }

        float m0 = e0, m1 = e1, m2 = e2, m3 = e3, m4 = e4, m5 = e5;
        #pragma unroll
        for (int off = 32; off; off >>= 1) {
            m0 = fmaxf(m0, __shfl_xor(m0, off, 64));
            m1 = fmaxf(m1, __shfl_xor(m1, off, 64));
            m2 = fmaxf(m2, __shfl_xor(m2, off, 64));
            m3 = fmaxf(m3, __shfl_xor(m3, off, 64));
            m4 = fmaxf(m4, __shfl_xor(m4, off, 64));
            m5 = fmaxf(m5, __shfl_xor(m5, off, 64));
        }
        float w0 = act ? __expf(e0 - m0) : 0.f;
        float w1 = act ? __expf(e1 - m1) : 0.f;
        float w2 = act ? __expf(e2 - m2) : 0.f;
        float w3 = act ? __expf(e3 - m3) : 0.f;
        float w4 = act ? __expf(e4 - m4) : 0.f;
        float w5 = act ? __expf(e5 - m5) : 0.f;
        float d0 = w0, d1 = w1, d2 = w2, d3 = w3, d4 = w4, d5 = w5;
        #pragma unroll
        for (int off = 32; off; off >>= 1) {
            d0 += __shfl_xor(d0, off, 64);  d1 += __shfl_xor(d1, off, 64);
            d2 += __shfl_xor(d2, off, 64);  d3 += __shfl_xor(d3, off, 64);
            d4 += __shfl_xor(d4, off, 64);  d5 += __shfl_xor(d5, off, 64);
        }
        w0 *= 1.f / (d0 + 1e-16f);  w1 *= 1.f / (d1 + 1e-16f);
        w2 *= 1.f / (d2 + 1e-16f);  w3 *= 1.f / (d3 + 1e-16f);
        w4 *= 1.f / (d4 + 1e-16f);  w5 *= 1.f / (d5 + 1e-16f);

        float a00 = 0, a01 = 0, a02 = 0, a03 = 0, a04 = 0, a05 = 0;
        float a10 = 0, a11 = 0, a12 = 0, a13 = 0, a14 = 0, a15 = 0;
        const float* xb = x + (lane << 1);   // channels c=2*lane, 2*lane+1

        float2 xa, xbv;
        {
            int s0 = __builtin_amdgcn_readlane(s, 0);
            xa = *(const float2*)(xb + (size_t)s0 * D);
        }
        xbv = make_float2(0.f, 0.f);
        if (nent > 1) {
            int s1 = __builtin_amdgcn_readlane(s, 1);
            xbv = *(const float2*)(xb + (size_t)s1 * D);
        }
        for (int j = 0; j < nent; j += 2) {
            float2 xn0 = make_float2(0.f, 0.f), xn1 = make_float2(0.f, 0.f);
            if (j + 2 < nent) {
                int s2 = __builtin_amdgcn_readlane(s, j + 2);
                xn0 = *(const float2*)(xb + (size_t)s2 * D);
            }
            if (j + 3 < nent) {
                int s3 = __builtin_amdgcn_readlane(s, j + 3);
                xn1 = *(const float2*)(xb + (size_t)s3 * D);
            }
            {
                float b0 = rlf(w0, j), b1 = rlf(w1, j), b2 = rlf(w2, j);
                float b3 = rlf(w3, j), b4 = rlf(w4, j), b5 = rlf(w5, j);
                a00 += b0 * xa.x; a10 += b0 * xa.y;
                a01 += b1 * xa.x; a11 += b1 * xa.y;
                a02 += b2 * xa.x; a12 += b2 * xa.y;
                a03 += b3 * xa.x; a13 += b3 * xa.y;
                a04 += b4 * xa.x; a14 += b4 * xa.y;
                a05 += b5 * xa.x; a15 += b5 * xa.y;
            }
            if (j + 1 < nent) {
                float b0 = rlf(w0, j + 1), b1 = rlf(w1, j + 1), b2 = rlf(w2, j + 1);
                float b3 = rlf(w3, j + 1), b4 = rlf(w4, j + 1), b5 = rlf(w5, j + 1);
                a00 += b0 * xbv.x; a10 += b0 * xbv.y;
                a01 += b1 * xbv.x; a11 += b1 * xbv.y;
                a02 += b2 * xbv.x; a12 += b2 * xbv.y;
                a03 += b3 * xbv.x; a13 += b3 * xbv.y;
                a04 += b4 * xbv.x; a14 += b4 * xbv.y;
                a05 += b5 * xbv.x; a15 += b5 * xbv.y;
            }
            xa = xn0; xbv = xn1;
        }
        int c = lane << 1;
        xsrow[0 * D + c] = (_Float16)a00;  xsrow[0 * D + c + 1] = (_Float16)a10;
        xsrow[1 * D + c] = (_Float16)a01;  xsrow[1 * D + c + 1] = (_Float16)a11;
        xsrow[2 * D + c] = (_Float16)a02;  xsrow[2 * D + c + 1] = (_Float16)a12;
        xsrow[3 * D + c] = (_Float16)a03;  xsrow[3 * D + c + 1] = (_Float16)a13;
        xsrow[4 * D + c] = (_Float16)a04;  xsrow[4 * D + c + 1] = (_Float16)a14;
        xsrow[5 * D + c] = (_Float16)a05;  xsrow[5 * D + c + 1] = (_Float16)a15;
    } else {
        // slow fallback (deg >= 64): channels c0=lane, c1=64+lane
        float m[H];
        #pragma unroll
        for (int h = 0; h < H; h++) {
            float e = a[(size_t)n * 12 + h] + adst[h];
            m[h] = (e > 0.f) ? e : 0.2f * e;
        }
        for (int j = 0; j < deg; j++) {
            int s = col[start + j];
            #pragma unroll
            for (int h = 0; h < H; h++) {
                float e = a[(size_t)s * 12 + h] + adst[h];
                e = (e > 0.f) ? e : 0.2f * e;
                m[h] = fmaxf(m[h], e);
            }
        }
        float d[H] = {0, 0, 0, 0, 0, 0};
        float acc0[H] = {0, 0, 0, 0, 0, 0};
        float acc1[H] = {0, 0, 0, 0, 0, 0};
        int c0 = lane, c1 = 64 + lane;
        for (int j = 0; j <= deg; j++) {
            int s = (j < deg) ? col[start + j] : n;
            float w[H];
            #pragma unroll
            for (int h = 0; h < H; h++) {
                float e = a[(size_t)s * 12 + h] + adst[h];
                e = (e > 0.f) ? e : 0.2f * e;
                w[h] = __expf(e - m[h]);
                d[h] += w[h];
            }
            float xv0 = x[(size_t)s * D + c0];
            float xv1 = x[(size_t)s * D + c1];
            #pragma unroll
            for (int h = 0; h < H; h++) {
                acc0[h] += w[h] * xv0;
                acc1[h] += w[h] * xv1;
            }
        }
        #pragma unroll
        for (int h = 0; h < H; h++) {
            float inv = 1.0f / (d[h] + 1e-16f);
            xsrow[h * D + c0] = (_Float16)(acc0[h] * inv);
            xsrow[h * D + c1] = (_Float16)(acc1[h] * inv);
        }
    }
}

// ---------------- fused layer: aggregate(16 nodes -> LDS) + MFMA GEMM + a ----------------
__global__ __launch_bounds__(512) void layer_kernel(const float* __restrict__ x,
                                                    const float* __restrict__ a_in,
                                                    const int* __restrict__ rowend,
                                                    const int* __restrict__ deg_,
                                                    const int* __restrict__ col,
                                                    const __half* __restrict__ bf,
                                                    const float* __restrict__ bias,
                                                    float* __restrict__ xout,
                                                    const __half* __restrict__ awf,
                                                    float* __restrict__ a_out, int M) {
    __shared__ _Float16 xs16[16][PADK];   // aggregated rows, plain layout
    __shared__ _Float16 xso[16][136];     // output rows (f16) for fused a
    const int wave = (int)(threadIdx.x >> 6);
    const int lane = (int)(threadIdx.x & 63);
    const int m0 = (int)(blockIdx.x << 4);

    // phase 1: each wave aggregates 2 nodes
    #pragma unroll
    for (int i = 0; i < 2; i++) {
        int row = wave * 2 + i;
        int n = m0 + row;
        if (n < M)
            aggregate_node(x, a_in, rowend, deg_, col, n, lane, &xs16[row][0]);
    }
    __syncthreads();

    // phase 2: GEMM — wave w owns col-tile w (cols w*16..w*16+15)
    f32x4 acc = {0.f, 0.f, 0.f, 0.f};
    const _Float16* ars = &xs16[lane & 15][(lane >> 4) << 3];
    const __half* bp = bf + (size_t)wave * 512 + (size_t)lane * 8;
    for (int t = 0; t < TSTEPS; t++) {
        f16x8 av = *(const f16x8*)(ars + t * 32);
        f16x8 bv = *(const f16x8*)(bp + (size_t)t * 4096);
        acc = __builtin_amdgcn_mfma_f32_16x16x32_f16(av, bv, acc, 0, 0, 0);
    }

    const float inv6 = 1.0f / 6.0f;
    const int cl = lane & 15;
    const int ccol = wave * 16 + cl;
    const int r0 = (lane >> 4) << 2;
    const float bs = bias[ccol];
    #pragma unroll
    for (int reg = 0; reg < 4; reg++) {
        int ml = r0 + reg;
        int m = m0 + ml;
        float v = acc[reg] * inv6 + bs;
        v = v > 0.f ? v : 0.f;
        if (m < M) out_store: ;
        if (m < M) xout[(size_t)m * D + ccol] = v; else v = 0.f;
        xso[ml][ccol] = (_Float16)v;
    }

    // phase 3: fused next-layer attention logits (wave 0)
    if (awf) {
        __syncthreads();
        if (wave == 0) {
            f32x4 ac = {0.f, 0.f, 0.f, 0.f};
            #pragma unroll
            for (int t = 0; t < 4; t++) {
                f16x8 av = *(const f16x8*)&xso[cl][t * 32 + ((lane >> 4) << 3)];
                f16x8 bv = *(const f16x8*)(awf + (size_t)t * 512 + (size_t)lane * 8);
                ac = __builtin_amdgcn_mfma_f32_16x16x32_f16(av, bv, ac, 0, 0, 0);
            }
            if (cl < 12) {
                #pragma unroll
                for (int reg = 0; reg < 4; reg++) {
                    int m = m0 + r0 + reg;
                    if (m < M) a_out[(size_t)m * 12 + cl] = ac[reg];
                }
            }
        }
    }
}

// ---------------- host ----------------

extern "C" void kernel_launch(void* const* d_in, const int* in_sizes, int n_in,
                              void* d_out, int out_size, void* d_ws, size_t ws_size,
                              hipStream_t stream) {
    const float* x_in = (const float*)d_in[0];
    const int* ei = (const int*)d_in[1];
    int N = in_sizes[0] / D;
    int E = in_sizes[1] / 2;
    const int* srcp = ei;
    const int* dstp = ei + E;

    size_t bf_halves_per_layer = (size_t)TSTEPS * 8 * 512;   // 98304

    float* ws = (float*)d_ws;
    float* bufA = ws;
    float* bufB = bufA + (size_t)N * D;
    float* abuf0 = bufB + (size_t)N * D;
    float* abuf1 = abuf0 + (size_t)N * 12;
    float* wa_all = abuf1 + (size_t)N * 12;       // 4*1536 floats
    __half* waf = (__half*)(wa_all + 4 * 1536);   // 3 layers x 2048 halves
    __half* w16f = waf + 3 * 2048;
    int* deg = (int*)(w16f + 4 * bf_halves_per_layer);
    int* rowptr = deg + N;
    int* col = rowptr + (N + 1);

    FoldArgs fa;
    for (int l = 0; l < 4; l++) {
        fa.W[l]  = (const float*)d_in[2 + 4 * l];
        fa.as[l] = (const float*)d_in[3 + 4 * l];
        fa.ad[l] = (const float*)d_in[4 + 4 * l];
    }

    // CSR build + fused prep
    hipMemsetAsync(deg, 0, (size_t)N * sizeof(int), stream);
    int histBlocks = (E + 255) / 256;
    hist_prep1_kernel<<<histBlocks + 24, 256, 0, stream>>>(dstp, deg, E, histBlocks, fa, wa_all);
    scan_kernel<<<1, 1024, 0, stream>>>(deg, rowptr, N);
    int scatBlocks = (E + 255) / 256;
    int caBlocks = (N + 3) / 4;
    scatter_prep2_kernel<<<scatBlocks + 3 + 192 + caBlocks, 256, 0, stream>>>(
        srcp, dstp, rowptr, col, E, scatBlocks, fa, wa_all, waf, w16f, x_in, abuf0, N);

    const float* xcur = x_in;
    float* acur = abuf0;
    float* anext = abuf1;
    for (int l = 0; l < 4; l++) {
        const float* b = (const float*)d_in[5 + 4 * l];
        float* xout = (l == 3) ? (float*)d_out : ((l & 1) ? bufB : bufA);
        const __half* awf = (l < 3) ? (waf + (size_t)l * 2048) : (const __half*)nullptr;

        layer_kernel<<<(N + 15) / 16, 512, 0, stream>>>(xcur, acur, rowptr, deg, col,
                                                        w16f + (size_t)l * bf_halves_per_layer,
                                                        b, xout, awf, anext, N);
        xcur = xout;
        float* tmp = acur; acur = anext; anext = tmp;
    }
}

// Round 10
// 175.178 us; speedup vs baseline: 53.4888x; 1.0312x over previous
//
#include <hip/hip_runtime.h>
#include <hip/hip_fp16.h>
#include <math.h>

#define H 6
#define D 128
#define K_ALL (H * D)   // 768
#define TSTEPS 24       // K_ALL / 32
#define PADK 776        // 768 + 8 halves pad -> conflict-free fragment reads
#define NPB 8           // nodes per block (1 per wave)

typedef _Float16 f16x8 __attribute__((ext_vector_type(8)));
typedef float f32x4 __attribute__((ext_vector_type(4)));

struct FoldArgs {
    const float* W[4];
    const float* as[4];
    const float* ad[4];
};

// ---------------- CSR build + fused prep ----------------

// blocks [0, histBlocks): histogram. blocks [histBlocks, +24): wa_all dots.
__global__ __launch_bounds__(256) void hist_prep1_kernel(const int* __restrict__ dst,
                                                         int* __restrict__ deg, int E,
                                                         int histBlocks, FoldArgs fa,
                                                         float* __restrict__ wa_all) {
    int b = blockIdx.x;
    int tid = threadIdx.x;
    if (b < histBlocks) {
        int e = b * 256 + tid;
        if (e < E) atomicAdd(&deg[dst[e]], 1);
    } else {
        int t = (b - histBlocks) * 256 + tid;   // < 6144
        if (t >= 4 * 1536) return;
        int l = t / 1536;
        int r = t % 1536;
        int k = r / 12, j = r % 12;
        int h = (j < 6) ? j : (j - 6);
        const float* att = (j < 6) ? fa.as[l] : fa.ad[l];
        const float* wrow = fa.W[l] + (size_t)k * K_ALL + h * D;
        const float* arow = att + h * D;
        float s = 0.f;
        #pragma unroll 8
        for (int c = 0; c < D; c++) s += wrow[c] * arow[c];
        wa_all[(size_t)l * 1536 + k * 12 + j] = s;
    }
}

// single-pass scan: thread i owns elements [i*16, i*16+16); 2 barriers total.
__global__ __launch_bounds__(1024) void scan_kernel(const int* __restrict__ deg,
                                                    int* __restrict__ rowptr, int n) {
    __shared__ int wsum[16];
    const int tid = threadIdx.x;
    const int lane = tid & 63;
    const int wv = tid >> 6;
    const int base = tid << 4;

    int v[16];
    int tot = 0;
    #pragma unroll
    for (int k = 0; k < 16; k++) {
        int i = base + k;
        int d = (i < n) ? deg[i] : 0;
        v[k] = tot;
        tot += d;
    }
    int s = tot;
    #pragma unroll
    for (int off = 1; off < 64; off <<= 1) {
        int t = __shfl_up(s, off, 64);
        if (lane >= off) s += t;
    }
    if (lane == 63) wsum[wv] = s;
    __syncthreads();
    if (tid < 16) {
        int t = wsum[tid];
        #pragma unroll
        for (int off = 1; off < 16; off <<= 1) {
            int u = __shfl_up(t, off, 64);
            if ((int)tid >= off) t += u;
        }
        wsum[tid] = t;
    }
    __syncthreads();
    int off0 = ((wv > 0) ? wsum[wv - 1] : 0) + s - tot;
    #pragma unroll
    for (int k = 0; k < 16; k++) {
        int i = base + k;
        if (i < n) rowptr[i] = off0 + v[k];
    }
}

// blocks: [0,scat): scatter | +3: waf pack | +192: bf pack | +caBlocks: layer-0 a
__global__ __launch_bounds__(256) void scatter_prep2_kernel(const int* __restrict__ src,
                                                            const int* __restrict__ dst,
                                                            int* __restrict__ rowcur,
                                                            int* __restrict__ col, int E,
                                                            int scatBlocks, FoldArgs fa,
                                                            const float* __restrict__ wa_all,
                                                            __half* __restrict__ waf,
                                                            __half* __restrict__ bf,
                                                            const float* __restrict__ x_in,
                                                            float* __restrict__ a0, int N) {
    __shared__ float swa[1536];
    int b = blockIdx.x;
    int tid = threadIdx.x;
    if (b < scatBlocks) {
        int e = b * 256 + tid;
        if (e < E) {
            int p = atomicAdd(&rowcur[dst[e]], 1);
            col[p] = src[e];
        }
        return;
    }
    int bb = b - scatBlocks;
    if (bb < 3) {
        // waf for layer L = bb+1
        int L = bb + 1;
        int lane = tid & 63;
        int t = tid >> 6;
        int j = lane & 15;
        const float* wl = wa_all + (size_t)L * 1536;
        f16x8 v;
        #pragma unroll
        for (int jj = 0; jj < 8; jj++) {
            int k = t * 32 + ((lane >> 4) << 3) + jj;
            float s = (j < 12) ? wl[k * 12 + j] : 0.f;
            v[jj] = (_Float16)s;
        }
        *(f16x8*)(waf + (size_t)bb * 2048 + (size_t)t * 512 + (size_t)lane * 8) = v;
        return;
    }
    bb -= 3;
    if (bb < 192) {
        int idx = bb * 256 + tid;    // < 49152
        int l63 = idx & 63;
        int ct = (idx >> 6) & 7;
        int t = (idx >> 9) % TSTEPS;
        int layer = idx / (TSTEPS * 8 * 64);
        const float* W = fa.W[layer];
        int c = ct * 16 + (l63 & 15);
        f16x8 v;
        #pragma unroll
        for (int j = 0; j < 8; j++) {
            int k = t * 32 + ((l63 >> 4) << 3) + j;
            v[j] = (_Float16)W[(size_t)(k & 127) * K_ALL + ((k >> 7) << 7) + c];
        }
        *(f16x8*)(bf + ((size_t)idx << 3)) = v;
        return;
    }
    bb -= 192;
    // layer-0 a: one wave per node
    for (int i = tid; i < 1536; i += 256) swa[i] = wa_all[i];
    __syncthreads();
    int lane = tid & 63;
    int wid = bb * 4 + (tid >> 6);
    if (wid >= N) return;
    float x0 = x_in[(size_t)wid * D + lane];
    float x1 = x_in[(size_t)wid * D + 64 + lane];
    #pragma unroll
    for (int j = 0; j < 12; j++) {
        float p = x0 * swa[lane * 12 + j] + x1 * swa[(64 + lane) * 12 + j];
        #pragma unroll
        for (int off = 32; off; off >>= 1) p += __shfl_xor(p, off, 64);
        if (lane == 0) a0[(size_t)wid * 12 + j] = p;
    }
}

__device__ __forceinline__ float rlf(float v, int j) {
    return __int_as_float(__builtin_amdgcn_readlane(__float_as_int(v), j));
}

// per-wave: aggregate node n (softmax over incoming edges + self loop),
// write normalized result as f16 PLAIN layout into LDS row xsrow[0..767].
__device__ __forceinline__ void aggregate_node(const float* __restrict__ x,
                                               const float* __restrict__ a,
                                               const int* __restrict__ rowend,
                                               const int* __restrict__ deg_,
                                               const int* __restrict__ col,
                                               int n, int lane,
                                               _Float16* __restrict__ xsrow) {
    const int deg = deg_[n];
    const int start = rowend[n] - deg;
    const int nent = deg + 1;

    float adst[H];
    #pragma unroll
    for (int h = 0; h < H; h++) adst[h] = a[(size_t)n * 12 + 6 + h];

    if (nent <= 64) {
        const bool act = lane < nent;
        int s = n;                          // lane 'deg' = self loop
        if (lane < deg) s = col[start + lane];

        const float* as_ = a + (size_t)s * 12;
        float4 v0 = *(const float4*)as_;
        float2 v1 = *(const float2*)(as_ + 4);
        float e0 = v0.x + adst[0], e1 = v0.y + adst[1], e2 = v0.z + adst[2];
        float e3 = v0.w + adst[3], e4 = v1.x + adst[4], e5 = v1.y + adst[5];
        e0 = e0 > 0.f ? e0 : 0.2f * e0;  e1 = e1 > 0.f ? e1 : 0.2f * e1;
        e2 = e2 > 0.f ? e2 : 0.2f * e2;  e3 = e3 > 0.f ? e3 : 0.2f * e3;
        e4 = e4 > 0.f ? e4 : 0.2f * e4;  e5 = e5 > 0.f ? e5 : 0.2f * e5;
        if (!act) { e0 = e1 = e2 = e3 = e4 = e5 = -1e30f; }

        float m0 = e0, m1 = e1, m2 = e2, m3 = e3, m4 = e4, m5 = e5;
        #pragma unroll
        for (int off = 32; off; off >>= 1) {
            m0 = fmaxf(m0, __shfl_xor(m0, off, 64));
            m1 = fmaxf(m1, __shfl_xor(m1, off, 64));
            m2 = fmaxf(m2, __shfl_xor(m2, off, 64));
            m3 = fmaxf(m3, __shfl_xor(m3, off, 64));
            m4 = fmaxf(m4, __shfl_xor(m4, off, 64));
            m5 = fmaxf(m5, __shfl_xor(m5, off, 64));
        }
        float w0 = act ? __expf(e0 - m0) : 0.f;
        float w1 = act ? __expf(e1 - m1) : 0.f;
        float w2 = act ? __expf(e2 - m2) : 0.f;
        float w3 = act ? __expf(e3 - m3) : 0.f;
        float w4 = act ? __expf(e4 - m4) : 0.f;
        float w5 = act ? __expf(e5 - m5) : 0.f;
        float d0 = w0, d1 = w1, d2 = w2, d3 = w3, d4 = w4, d5 = w5;
        #pragma unroll
        for (int off = 32; off; off >>= 1) {
            d0 += __shfl_xor(d0, off, 64);  d1 += __shfl_xor(d1, off, 64);
            d2 += __shfl_xor(d2, off, 64);  d3 += __shfl_xor(d3, off, 64);
            d4 += __shfl_xor(d4, off, 64);  d5 += __shfl_xor(d5, off, 64);
        }
        w0 *= 1.f / (d0 + 1e-16f);  w1 *= 1.f / (d1 + 1e-16f);
        w2 *= 1.f / (d2 + 1e-16f);  w3 *= 1.f / (d3 + 1e-16f);
        w4 *= 1.f / (d4 + 1e-16f);  w5 *= 1.f / (d5 + 1e-16f);

        float a00 = 0, a01 = 0, a02 = 0, a03 = 0, a04 = 0, a05 = 0;
        float a10 = 0, a11 = 0, a12 = 0, a13 = 0, a14 = 0, a15 = 0;
        const float* xb = x + (lane << 1);   // channels c=2*lane, 2*lane+1

        float2 xa, xbv;
        {
            int s0 = __builtin_amdgcn_readlane(s, 0);
            xa = *(const float2*)(xb + (size_t)s0 * D);
        }
        xbv = make_float2(0.f, 0.f);
        if (nent > 1) {
            int s1 = __builtin_amdgcn_readlane(s, 1);
            xbv = *(const float2*)(xb + (size_t)s1 * D);
        }
        for (int j = 0; j < nent; j += 2) {
            float2 xn0 = make_float2(0.f, 0.f), xn1 = make_float2(0.f, 0.f);
            if (j + 2 < nent) {
                int s2 = __builtin_amdgcn_readlane(s, j + 2);
                xn0 = *(const float2*)(xb + (size_t)s2 * D);
            }
            if (j + 3 < nent) {
                int s3 = __builtin_amdgcn_readlane(s, j + 3);
                xn1 = *(const float2*)(xb + (size_t)s3 * D);
            }
            {
                float b0 = rlf(w0, j), b1 = rlf(w1, j), b2 = rlf(w2, j);
                float b3 = rlf(w3, j), b4 = rlf(w4, j), b5 = rlf(w5, j);
                a00 += b0 * xa.x; a10 += b0 * xa.y;
                a01 += b1 * xa.x; a11 += b1 * xa.y;
                a02 += b2 * xa.x; a12 += b2 * xa.y;
                a03 += b3 * xa.x; a13 += b3 * xa.y;
                a04 += b4 * xa.x; a14 += b4 * xa.y;
                a05 += b5 * xa.x; a15 += b5 * xa.y;
            }
            if (j + 1 < nent) {
                float b0 = rlf(w0, j + 1), b1 = rlf(w1, j + 1), b2 = rlf(w2, j + 1);
                float b3 = rlf(w3, j + 1), b4 = rlf(w4, j + 1), b5 = rlf(w5, j + 1);
                a00 += b0 * xbv.x; a10 += b0 * xbv.y;
                a01 += b1 * xbv.x; a11 += b1 * xbv.y;
                a02 += b2 * xbv.x; a12 += b2 * xbv.y;
                a03 += b3 * xbv.x; a13 += b3 * xbv.y;
                a04 += b4 * xbv.x; a14 += b4 * xbv.y;
                a05 += b5 * xbv.x; a15 += b5 * xbv.y;
            }
            xa = xn0; xbv = xn1;
        }
        int c = lane << 1;
        xsrow[0 * D + c] = (_Float16)a00;  xsrow[0 * D + c + 1] = (_Float16)a10;
        xsrow[1 * D + c] = (_Float16)a01;  xsrow[1 * D + c + 1] = (_Float16)a11;
        xsrow[2 * D + c] = (_Float16)a02;  xsrow[2 * D + c + 1] = (_Float16)a12;
        xsrow[3 * D + c] = (_Float16)a03;  xsrow[3 * D + c + 1] = (_Float16)a13;
        xsrow[4 * D + c] = (_Float16)a04;  xsrow[4 * D + c + 1] = (_Float16)a14;
        xsrow[5 * D + c] = (_Float16)a05;  xsrow[5 * D + c + 1] = (_Float16)a15;
    } else {
        // slow fallback (deg >= 64): channels c0=lane, c1=64+lane
        float m[H];
        #pragma unroll
        for (int h = 0; h < H; h++) {
            float e = a[(size_t)n * 12 + h] + adst[h];
            m[h] = (e > 0.f) ? e : 0.2f * e;
        }
        for (int j = 0; j < deg; j++) {
            int s = col[start + j];
            #pragma unroll
            for (int h = 0; h < H; h++) {
                float e = a[(size_t)s * 12 + h] + adst[h];
                e = (e > 0.f) ? e : 0.2f * e;
                m[h] = fmaxf(m[h], e);
            }
        }
        float d[H] = {0, 0, 0, 0, 0, 0};
        float acc0[H] = {0, 0, 0, 0, 0, 0};
        float acc1[H] = {0, 0, 0, 0, 0, 0};
        int c0 = lane, c1 = 64 + lane;
        for (int j = 0; j <= deg; j++) {
            int s = (j < deg) ? col[start + j] : n;
            float w[H];
            #pragma unroll
            for (int h = 0; h < H; h++) {
                float e = a[(size_t)s * 12 + h] + adst[h];
                e = (e > 0.f) ? e : 0.2f * e;
                w[h] = __expf(e - m[h]);
                d[h] += w[h];
            }
            float xv0 = x[(size_t)s * D + c0];
            float xv1 = x[(size_t)s * D + c1];
            #pragma unroll
            for (int h = 0; h < H; h++) {
                acc0[h] += w[h] * xv0;
                acc1[h] += w[h] * xv1;
            }
        }
        #pragma unroll
        for (int h = 0; h < H; h++) {
            float inv = 1.0f / (d[h] + 1e-16f);
            xsrow[h * D + c0] = (_Float16)(acc0[h] * inv);
            xsrow[h * D + c1] = (_Float16)(acc1[h] * inv);
        }
    }
}

// ---------------- fused layer: aggregate(8 nodes -> LDS) + MFMA GEMM + a ----------------
// 8 waves, wave w aggregates node m0+w (rows 0..7 valid; A rows 8..15 are
// garbage and pollute only D rows 8..15, which are never stored).
__global__ __launch_bounds__(512) void layer_kernel(const float* __restrict__ x,
                                                    const float* __restrict__ a_in,
                                                    const int* __restrict__ rowend,
                                                    const int* __restrict__ deg_,
                                                    const int* __restrict__ col,
                                                    const __half* __restrict__ bf,
                                                    const float* __restrict__ bias,
                                                    float* __restrict__ xout,
                                                    const __half* __restrict__ awf,
                                                    float* __restrict__ a_out, int M) {
    __shared__ _Float16 xs16[16][PADK];   // rows 0..7 aggregated; 8..15 garbage
    __shared__ _Float16 xso[16][136];     // output rows (f16) for fused a
    const int wave = (int)(threadIdx.x >> 6);
    const int lane = (int)(threadIdx.x & 63);
    const int m0 = (int)(blockIdx.x << 3);

    // phase 1: each wave aggregates 1 node
    {
        int n = m0 + wave;
        if (n < M)
            aggregate_node(x, a_in, rowend, deg_, col, n, lane, &xs16[wave][0]);
    }
    __syncthreads();

    // phase 2: GEMM — wave w owns col-tile w (cols w*16..w*16+15)
    f32x4 acc = {0.f, 0.f, 0.f, 0.f};
    const _Float16* ars = &xs16[lane & 15][(lane >> 4) << 3];
    const __half* bp = bf + (size_t)wave * 512 + (size_t)lane * 8;
    for (int t = 0; t < TSTEPS; t++) {
        f16x8 av = *(const f16x8*)(ars + t * 32);
        f16x8 bv = *(const f16x8*)(bp + (size_t)t * 4096);
        acc = __builtin_amdgcn_mfma_f32_16x16x32_f16(av, bv, acc, 0, 0, 0);
    }

    const float inv6 = 1.0f / 6.0f;
    const int cl = lane & 15;
    const int ccol = wave * 16 + cl;
    const int r0 = (lane >> 4) << 2;
    const float bs = bias[ccol];
    #pragma unroll
    for (int reg = 0; reg < 4; reg++) {
        int ml = r0 + reg;
        int m = m0 + ml;
        float v = acc[reg] * inv6 + bs;
        v = v > 0.f ? v : 0.f;
        if (ml < NPB && m < M) xout[(size_t)m * D + ccol] = v;
        xso[ml][ccol] = (_Float16)v;
    }

    // phase 3: fused next-layer attention logits (wave 0)
    if (awf) {
        __syncthreads();
        if (wave == 0) {
            f32x4 ac = {0.f, 0.f, 0.f, 0.f};
            #pragma unroll
            for (int t = 0; t < 4; t++) {
                f16x8 av = *(const f16x8*)&xso[cl][t * 32 + ((lane >> 4) << 3)];
                f16x8 bv = *(const f16x8*)(awf + (size_t)t * 512 + (size_t)lane * 8);
                ac = __builtin_amdgcn_mfma_f32_16x16x32_f16(av, bv, ac, 0, 0, 0);
            }
            if (cl < 12) {
                #pragma unroll
                for (int reg = 0; reg < 4; reg++) {
                    int ml = r0 + reg;
                    int m = m0 + ml;
                    if (ml < NPB && m < M) a_out[(size_t)m * 12 + cl] = ac[reg];
                }
            }
        }
    }
}

// ---------------- host ----------------

extern "C" void kernel_launch(void* const* d_in, const int* in_sizes, int n_in,
                              void* d_out, int out_size, void* d_ws, size_t ws_size,
                              hipStream_t stream) {
    const float* x_in = (const float*)d_in[0];
    const int* ei = (const int*)d_in[1];
    int N = in_sizes[0] / D;
    int E = in_sizes[1] / 2;
    const int* srcp = ei;
    const int* dstp = ei + E;

    size_t bf_halves_per_layer = (size_t)TSTEPS * 8 * 512;   // 98304

    float* ws = (float*)d_ws;
    float* bufA = ws;
    float* bufB = bufA + (size_t)N * D;
    float* abuf0 = bufB + (size_t)N * D;
    float* abuf1 = abuf0 + (size_t)N * 12;
    float* wa_all = abuf1 + (size_t)N * 12;       // 4*1536 floats
    __half* waf = (__half*)(wa_all + 4 * 1536);   // 3 layers x 2048 halves
    __half* w16f = waf + 3 * 2048;
    int* deg = (int*)(w16f + 4 * bf_halves_per_layer);
    int* rowptr = deg + N;
    int* col = rowptr + (N + 1);

    FoldArgs fa;
    for (int l = 0; l < 4; l++) {
        fa.W[l]  = (const float*)d_in[2 + 4 * l];
        fa.as[l] = (const float*)d_in[3 + 4 * l];
        fa.ad[l] = (const float*)d_in[4 + 4 * l];
    }

    // CSR build + fused prep
    hipMemsetAsync(deg, 0, (size_t)N * sizeof(int), stream);
    int histBlocks = (E + 255) / 256;
    hist_prep1_kernel<<<histBlocks + 24, 256, 0, stream>>>(dstp, deg, E, histBlocks, fa, wa_all);
    scan_kernel<<<1, 1024, 0, stream>>>(deg, rowptr, N);
    int scatBlocks = (E + 255) / 256;
    int caBlocks = (N + 3) / 4;
    scatter_prep2_kernel<<<scatBlocks + 3 + 192 + caBlocks, 256, 0, stream>>>(
        srcp, dstp, rowptr, col, E, scatBlocks, fa, wa_all, waf, w16f, x_in, abuf0, N);

    const float* xcur = x_in;
    float* acur = abuf0;
    float* anext = abuf1;
    for (int l = 0; l < 4; l++) {
        const float* b = (const float*)d_in[5 + 4 * l];
        float* xout = (l == 3) ? (float*)d_out : ((l & 1) ? bufB : bufA);
        const __half* awf = (l < 3) ? (waf + (size_t)l * 2048) : (const __half*)nullptr;

        layer_kernel<<<(N + NPB - 1) / NPB, 512, 0, stream>>>(xcur, acur, rowptr, deg, col,
                                                              w16f + (size_t)l * bf_halves_per_layer,
                                                              b, xout, awf, anext, N);
        xcur = xout;
        float* tmp = acur; acur = anext; anext = tmp;
    }
}

// Round 11
// 174.617 us; speedup vs baseline: 53.6607x; 1.0032x over previous
//
#include <hip/hip_runtime.h>
#include <hip/hip_fp16.h>
#include <math.h>

#define H 6
#define D 128
#define K_ALL (H * D)   // 768
#define TSTEPS 24       // K_ALL / 32
#define PADK 776        // 768 + 8 halves pad -> conflict-free fragment reads
#define NPB 8           // nodes per block (1 per wave)

typedef _Float16 f16x8 __attribute__((ext_vector_type(8)));
typedef float f32x4 __attribute__((ext_vector_type(4)));

struct FoldArgs {
    const float* W[4];
    const float* as[4];
    const float* ad[4];
};

// ---------------- CSR build + fused prep ----------------

// custom zero: the runtime's fillBufferAligned for a 40KB memset showed
// 44 us in rocprof (r10, _ord 141); this does it in ~1-2 us.
__global__ __launch_bounds__(256) void zero_kernel(int4* __restrict__ p, int n4) {
    int i = blockIdx.x * 256 + threadIdx.x;
    if (i < n4) p[i] = make_int4(0, 0, 0, 0);
}

// blocks [0, histBlocks): histogram. blocks [histBlocks, +24): wa_all dots.
__global__ __launch_bounds__(256) void hist_prep1_kernel(const int* __restrict__ dst,
                                                         int* __restrict__ deg, int E,
                                                         int histBlocks, FoldArgs fa,
                                                         float* __restrict__ wa_all) {
    int b = blockIdx.x;
    int tid = threadIdx.x;
    if (b < histBlocks) {
        int e = b * 256 + tid;
        if (e < E) atomicAdd(&deg[dst[e]], 1);
    } else {
        int t = (b - histBlocks) * 256 + tid;   // < 6144
        if (t >= 4 * 1536) return;
        int l = t / 1536;
        int r = t % 1536;
        int k = r / 12, j = r % 12;
        int h = (j < 6) ? j : (j - 6);
        const float* att = (j < 6) ? fa.as[l] : fa.ad[l];
        const float* wrow = fa.W[l] + (size_t)k * K_ALL + h * D;
        const float* arow = att + h * D;
        float s = 0.f;
        #pragma unroll 8
        for (int c = 0; c < D; c++) s += wrow[c] * arow[c];
        wa_all[(size_t)l * 1536 + k * 12 + j] = s;
    }
}

// single-pass scan: thread i owns elements [i*16, i*16+16); 2 barriers total.
__global__ __launch_bounds__(1024) void scan_kernel(const int* __restrict__ deg,
                                                    int* __restrict__ rowptr, int n) {
    __shared__ int wsum[16];
    const int tid = threadIdx.x;
    const int lane = tid & 63;
    const int wv = tid >> 6;
    const int base = tid << 4;

    int v[16];
    int tot = 0;
    #pragma unroll
    for (int k = 0; k < 16; k++) {
        int i = base + k;
        int d = (i < n) ? deg[i] : 0;
        v[k] = tot;
        tot += d;
    }
    int s = tot;
    #pragma unroll
    for (int off = 1; off < 64; off <<= 1) {
        int t = __shfl_up(s, off, 64);
        if (lane >= off) s += t;
    }
    if (lane == 63) wsum[wv] = s;
    __syncthreads();
    if (tid < 16) {
        int t = wsum[tid];
        #pragma unroll
        for (int off = 1; off < 16; off <<= 1) {
            int u = __shfl_up(t, off, 64);
            if ((int)tid >= off) t += u;
        }
        wsum[tid] = t;
    }
    __syncthreads();
    int off0 = ((wv > 0) ? wsum[wv - 1] : 0) + s - tot;
    #pragma unroll
    for (int k = 0; k < 16; k++) {
        int i = base + k;
        if (i < n) rowptr[i] = off0 + v[k];
    }
}

// blocks: [0,scat): scatter | +3: waf pack | +192: bf pack | +caBlocks: layer-0 a
__global__ __launch_bounds__(256) void scatter_prep2_kernel(const int* __restrict__ src,
                                                            const int* __restrict__ dst,
                                                            int* __restrict__ rowcur,
                                                            int* __restrict__ col, int E,
                                                            int scatBlocks, FoldArgs fa,
                                                            const float* __restrict__ wa_all,
                                                            __half* __restrict__ waf,
                                                            __half* __restrict__ bf,
                                                            const float* __restrict__ x_in,
                                                            float* __restrict__ a0, int N) {
    __shared__ float swa[1536];
    int b = blockIdx.x;
    int tid = threadIdx.x;
    if (b < scatBlocks) {
        int e = b * 256 + tid;
        if (e < E) {
            int p = atomicAdd(&rowcur[dst[e]], 1);
            col[p] = src[e];
        }
        return;
    }
    int bb = b - scatBlocks;
    if (bb < 3) {
        // waf for layer L = bb+1
        int L = bb + 1;
        int lane = tid & 63;
        int t = tid >> 6;
        int j = lane & 15;
        const float* wl = wa_all + (size_t)L * 1536;
        f16x8 v;
        #pragma unroll
        for (int jj = 0; jj < 8; jj++) {
            int k = t * 32 + ((lane >> 4) << 3) + jj;
            float s = (j < 12) ? wl[k * 12 + j] : 0.f;
            v[jj] = (_Float16)s;
        }
        *(f16x8*)(waf + (size_t)bb * 2048 + (size_t)t * 512 + (size_t)lane * 8) = v;
        return;
    }
    bb -= 3;
    if (bb < 192) {
        int idx = bb * 256 + tid;    // < 49152
        int l63 = idx & 63;
        int ct = (idx >> 6) & 7;
        int t = (idx >> 9) % TSTEPS;
        int layer = idx / (TSTEPS * 8 * 64);
        const float* W = fa.W[layer];
        int c = ct * 16 + (l63 & 15);
        f16x8 v;
        #pragma unroll
        for (int j = 0; j < 8; j++) {
            int k = t * 32 + ((l63 >> 4) << 3) + j;
            v[j] = (_Float16)W[(size_t)(k & 127) * K_ALL + ((k >> 7) << 7) + c];
        }
        *(f16x8*)(bf + ((size_t)idx << 3)) = v;
        return;
    }
    bb -= 192;
    // layer-0 a: one wave per node
    for (int i = tid; i < 1536; i += 256) swa[i] = wa_all[i];
    __syncthreads();
    int lane = tid & 63;
    int wid = bb * 4 + (tid >> 6);
    if (wid >= N) return;
    float x0 = x_in[(size_t)wid * D + lane];
    float x1 = x_in[(size_t)wid * D + 64 + lane];
    #pragma unroll
    for (int j = 0; j < 12; j++) {
        float p = x0 * swa[lane * 12 + j] + x1 * swa[(64 + lane) * 12 + j];
        #pragma unroll
        for (int off = 32; off; off >>= 1) p += __shfl_xor(p, off, 64);
        if (lane == 0) a0[(size_t)wid * 12 + j] = p;
    }
}

__device__ __forceinline__ float rlf(float v, int j) {
    return __int_as_float(__builtin_amdgcn_readlane(__float_as_int(v), j));
}

// per-wave: aggregate node n (softmax over incoming edges + self loop),
// write normalized result as f16 PLAIN layout into LDS row xsrow[0..767].
__device__ __forceinline__ void aggregate_node(const float* __restrict__ x,
                                               const float* __restrict__ a,
                                               const int* __restrict__ rowend,
                                               const int* __restrict__ deg_,
                                               const int* __restrict__ col,
                                               int n, int lane,
                                               _Float16* __restrict__ xsrow) {
    const int deg = deg_[n];
    const int start = rowend[n] - deg;
    const int nent = deg + 1;

    float adst[H];
    #pragma unroll
    for (int h = 0; h < H; h++) adst[h] = a[(size_t)n * 12 + 6 + h];

    if (nent <= 64) {
        const bool act = lane < nent;
        int s = n;                          // lane 'deg' = self loop
        if (lane < deg) s = col[start + lane];

        const float* as_ = a + (size_t)s * 12;
        float4 v0 = *(const float4*)as_;
        float2 v1 = *(const float2*)(as_ + 4);
        float e0 = v0.x + adst[0], e1 = v0.y + adst[1], e2 = v0.z + adst[2];
        float e3 = v0.w + adst[3], e4 = v1.x + adst[4], e5 = v1.y + adst[5];
        e0 = e0 > 0.f ? e0 : 0.2f * e0;  e1 = e1 > 0.f ? e1 : 0.2f * e1;
        e2 = e2 > 0.f ? e2 : 0.2f * e2;  e3 = e3 > 0.f ? e3 : 0.2f * e3;
        e4 = e4 > 0.f ? e4 : 0.2f * e4;  e5 = e5 > 0.f ? e5 : 0.2f * e5;
        if (!act) { e0 = e1 = e2 = e3 = e4 = e5 = -1e30f; }

        float m0 = e0, m1 = e1, m2 = e2, m3 = e3, m4 = e4, m5 = e5;
        #pragma unroll
        for (int off = 32; off; off >>= 1) {
            m0 = fmaxf(m0, __shfl_xor(m0, off, 64));
            m1 = fmaxf(m1, __shfl_xor(m1, off, 64));
            m2 = fmaxf(m2, __shfl_xor(m2, off, 64));
            m3 = fmaxf(m3, __shfl_xor(m3, off, 64));
            m4 = fmaxf(m4, __shfl_xor(m4, off, 64));
            m5 = fmaxf(m5, __shfl_xor(m5, off, 64));
        }
        float w0 = act ? __expf(e0 - m0) : 0.f;
        float w1 = act ? __expf(e1 - m1) : 0.f;
        float w2 = act ? __expf(e2 - m2) : 0.f;
        float w3 = act ? __expf(e3 - m3) : 0.f;
        float w4 = act ? __expf(e4 - m4) : 0.f;
        float w5 = act ? __expf(e5 - m5) : 0.f;
        float d0 = w0, d1 = w1, d2 = w2, d3 = w3, d4 = w4, d5 = w5;
        #pragma unroll
        for (int off = 32; off; off >>= 1) {
            d0 += __shfl_xor(d0, off, 64);  d1 += __shfl_xor(d1, off, 64);
            d2 += __shfl_xor(d2, off, 64);  d3 += __shfl_xor(d3, off, 64);
            d4 += __shfl_xor(d4, off, 64);  d5 += __shfl_xor(d5, off, 64);
        }
        w0 *= 1.f / (d0 + 1e-16f);  w1 *= 1.f / (d1 + 1e-16f);
        w2 *= 1.f / (d2 + 1e-16f);  w3 *= 1.f / (d3 + 1e-16f);
        w4 *= 1.f / (d4 + 1e-16f);  w5 *= 1.f / (d5 + 1e-16f);

        float a00 = 0, a01 = 0, a02 = 0, a03 = 0, a04 = 0, a05 = 0;
        float a10 = 0, a11 = 0, a12 = 0, a13 = 0, a14 = 0, a15 = 0;
        const float* xb = x + (lane << 1);   // channels c=2*lane, 2*lane+1

        float2 xa, xbv;
        {
            int s0 = __builtin_amdgcn_readlane(s, 0);
            xa = *(const float2*)(xb + (size_t)s0 * D);
        }
        xbv = make_float2(0.f, 0.f);
        if (nent > 1) {
            int s1 = __builtin_amdgcn_readlane(s, 1);
            xbv = *(const float2*)(xb + (size_t)s1 * D);
        }
        for (int j = 0; j < nent; j += 2) {
            float2 xn0 = make_float2(0.f, 0.f), xn1 = make_float2(0.f, 0.f);
            if (j + 2 < nent) {
                int s2 = __builtin_amdgcn_readlane(s, j + 2);
                xn0 = *(const float2*)(xb + (size_t)s2 * D);
            }
            if (j + 3 < nent) {
                int s3 = __builtin_amdgcn_readlane(s, j + 3);
                xn1 = *(const float2*)(xb + (size_t)s3 * D);
            }
            {
                float b0 = rlf(w0, j), b1 = rlf(w1, j), b2 = rlf(w2, j);
                float b3 = rlf(w3, j), b4 = rlf(w4, j), b5 = rlf(w5, j);
                a00 += b0 * xa.x; a10 += b0 * xa.y;
                a01 += b1 * xa.x; a11 += b1 * xa.y;
                a02 += b2 * xa.x; a12 += b2 * xa.y;
                a03 += b3 * xa.x; a13 += b3 * xa.y;
                a04 += b4 * xa.x; a14 += b4 * xa.y;
                a05 += b5 * xa.x; a15 += b5 * xa.y;
            }
            if (j + 1 < nent) {
                float b0 = rlf(w0, j + 1), b1 = rlf(w1, j + 1), b2 = rlf(w2, j + 1);
                float b3 = rlf(w3, j + 1), b4 = rlf(w4, j + 1), b5 = rlf(w5, j + 1);
                a00 += b0 * xbv.x; a10 += b0 * xbv.y;
                a01 += b1 * xbv.x; a11 += b1 * xbv.y;
                a02 += b2 * xbv.x; a12 += b2 * xbv.y;
                a03 += b3 * xbv.x; a13 += b3 * xbv.y;
                a04 += b4 * xbv.x; a14 += b4 * xbv.y;
                a05 += b5 * xbv.x; a15 += b5 * xbv.y;
            }
            xa = xn0; xbv = xn1;
        }
        int c = lane << 1;
        xsrow[0 * D + c] = (_Float16)a00;  xsrow[0 * D + c + 1] = (_Float16)a10;
        xsrow[1 * D + c] = (_Float16)a01;  xsrow[1 * D + c + 1] = (_Float16)a11;
        xsrow[2 * D + c] = (_Float16)a02;  xsrow[2 * D + c + 1] = (_Float16)a12;
        xsrow[3 * D + c] = (_Float16)a03;  xsrow[3 * D + c + 1] = (_Float16)a13;
        xsrow[4 * D + c] = (_Float16)a04;  xsrow[4 * D + c + 1] = (_Float16)a14;
        xsrow[5 * D + c] = (_Float16)a05;  xsrow[5 * D + c + 1] = (_Float16)a15;
    } else {
        // slow fallback (deg >= 64): channels c0=lane, c1=64+lane
        float m[H];
        #pragma unroll
        for (int h = 0; h < H; h++) {
            float e = a[(size_t)n * 12 + h] + adst[h];
            m[h] = (e > 0.f) ? e : 0.2f * e;
        }
        for (int j = 0; j < deg; j++) {
            int s = col[start + j];
            #pragma unroll
            for (int h = 0; h < H; h++) {
                float e = a[(size_t)s * 12 + h] + adst[h];
                e = (e > 0.f) ? e : 0.2f * e;
                m[h] = fmaxf(m[h], e);
            }
        }
        float d[H] = {0, 0, 0, 0, 0, 0};
        float acc0[H] = {0, 0, 0, 0, 0, 0};
        float acc1[H] = {0, 0, 0, 0, 0, 0};
        int c0 = lane, c1 = 64 + lane;
        for (int j = 0; j <= deg; j++) {
            int s = (j < deg) ? col[start + j] : n;
            float w[H];
            #pragma unroll
            for (int h = 0; h < H; h++) {
                float e = a[(size_t)s * 12 + h] + adst[h];
                e = (e > 0.f) ? e : 0.2f * e;
                w[h] = __expf(e - m[h]);
                d[h] += w[h];
            }
            float xv0 = x[(size_t)s * D + c0];
            float xv1 = x[(size_t)s * D + c1];
            #pragma unroll
            for (int h = 0; h < H; h++) {
                acc0[h] += w[h] * xv0;
                acc1[h] += w[h] * xv1;
            }
        }
        #pragma unroll
        for (int h = 0; h < H; h++) {
            float inv = 1.0f / (d[h] + 1e-16f);
            xsrow[h * D + c0] = (_Float16)(acc0[h] * inv);
            xsrow[h * D + c1] = (_Float16)(acc1[h] * inv);
        }
    }
}

// ---------------- fused layer: aggregate(8 nodes -> LDS) + MFMA GEMM + a ----------------
// 8 waves, wave w aggregates node m0+w (rows 0..7 valid; A rows 8..15 are
// garbage and pollute only D rows 8..15, which are never stored).
__global__ __launch_bounds__(512) void layer_kernel(const float* __restrict__ x,
                                                    const float* __restrict__ a_in,
                                                    const int* __restrict__ rowend,
                                                    const int* __restrict__ deg_,
                                                    const int* __restrict__ col,
                                                    const __half* __restrict__ bf,
                                                    const float* __restrict__ bias,
                                                    float* __restrict__ xout,
                                                    const __half* __restrict__ awf,
                                                    float* __restrict__ a_out, int M) {
    __shared__ _Float16 xs16[16][PADK];   // rows 0..7 aggregated; 8..15 garbage
    __shared__ _Float16 xso[16][136];     // output rows (f16) for fused a
    const int wave = (int)(threadIdx.x >> 6);
    const int lane = (int)(threadIdx.x & 63);
    const int m0 = (int)(blockIdx.x << 3);

    // phase 1: each wave aggregates 1 node
    {
        int n = m0 + wave;
        if (n < M)
            aggregate_node(x, a_in, rowend, deg_, col, n, lane, &xs16[wave][0]);
    }
    __syncthreads();

    // phase 2: GEMM — wave w owns col-tile w (cols w*16..w*16+15)
    f32x4 acc = {0.f, 0.f, 0.f, 0.f};
    const _Float16* ars = &xs16[lane & 15][(lane >> 4) << 3];
    const __half* bp = bf + (size_t)wave * 512 + (size_t)lane * 8;
    for (int t = 0; t < TSTEPS; t++) {
        f16x8 av = *(const f16x8*)(ars + t * 32);
        f16x8 bv = *(const f16x8*)(bp + (size_t)t * 4096);
        acc = __builtin_amdgcn_mfma_f32_16x16x32_f16(av, bv, acc, 0, 0, 0);
    }

    const float inv6 = 1.0f / 6.0f;
    const int cl = lane & 15;
    const int ccol = wave * 16 + cl;
    const int r0 = (lane >> 4) << 2;
    const float bs = bias[ccol];
    #pragma unroll
    for (int reg = 0; reg < 4; reg++) {
        int ml = r0 + reg;
        int m = m0 + ml;
        float v = acc[reg] * inv6 + bs;
        v = v > 0.f ? v : 0.f;
        if (ml < NPB && m < M) xout[(size_t)m * D + ccol] = v;
        xso[ml][ccol] = (_Float16)v;
    }

    // phase 3: fused next-layer attention logits (wave 0)
    if (awf) {
        __syncthreads();
        if (wave == 0) {
            f32x4 ac = {0.f, 0.f, 0.f, 0.f};
            #pragma unroll
            for (int t = 0; t < 4; t++) {
                f16x8 av = *(const f16x8*)&xso[cl][t * 32 + ((lane >> 4) << 3)];
                f16x8 bv = *(const f16x8*)(awf + (size_t)t * 512 + (size_t)lane * 8);
                ac = __builtin_amdgcn_mfma_f32_16x16x32_f16(av, bv, ac, 0, 0, 0);
            }
            if (cl < 12) {
                #pragma unroll
                for (int reg = 0; reg < 4; reg++) {
                    int ml = r0 + reg;
                    int m = m0 + ml;
                    if (ml < NPB && m < M) a_out[(size_t)m * 12 + cl] = ac[reg];
                }
            }
        }
    }
}

// ---------------- host ----------------

extern "C" void kernel_launch(void* const* d_in, const int* in_sizes, int n_in,
                              void* d_out, int out_size, void* d_ws, size_t ws_size,
                              hipStream_t stream) {
    const float* x_in = (const float*)d_in[0];
    const int* ei = (const int*)d_in[1];
    int N = in_sizes[0] / D;
    int E = in_sizes[1] / 2;
    const int* srcp = ei;
    const int* dstp = ei + E;

    size_t bf_halves_per_layer = (size_t)TSTEPS * 8 * 512;   // 98304

    float* ws = (float*)d_ws;
    float* bufA = ws;
    float* bufB = bufA + (size_t)N * D;
    float* abuf0 = bufB + (size_t)N * D;
    float* abuf1 = abuf0 + (size_t)N * 12;
    float* wa_all = abuf1 + (size_t)N * 12;       // 4*1536 floats
    __half* waf = (__half*)(wa_all + 4 * 1536);   // 3 layers x 2048 halves
    __half* w16f = waf + 3 * 2048;
    int* deg = (int*)(w16f + 4 * bf_halves_per_layer);
    int* rowptr = deg + N;
    int* col = rowptr + (N + 1);

    FoldArgs fa;
    for (int l = 0; l < 4; l++) {
        fa.W[l]  = (const float*)d_in[2 + 4 * l];
        fa.as[l] = (const float*)d_in[3 + 4 * l];
        fa.ad[l] = (const float*)d_in[4 + 4 * l];
    }

    // CSR build + fused prep (custom zero kernel instead of hipMemsetAsync)
    int n4 = (N + 3) / 4;
    zero_kernel<<<(n4 + 255) / 256, 256, 0, stream>>>((int4*)deg, n4);
    int histBlocks = (E + 255) / 256;
    hist_prep1_kernel<<<histBlocks + 24, 256, 0, stream>>>(dstp, deg, E, histBlocks, fa, wa_all);
    scan_kernel<<<1, 1024, 0, stream>>>(deg, rowptr, N);
    int scatBlocks = (E + 255) / 256;
    int caBlocks = (N + 3) / 4;
    scatter_prep2_kernel<<<scatBlocks + 3 + 192 + caBlocks, 256, 0, stream>>>(
        srcp, dstp, rowptr, col, E, scatBlocks, fa, wa_all, waf, w16f, x_in, abuf0, N);

    const float* xcur = x_in;
    float* acur = abuf0;
    float* anext = abuf1;
    for (int l = 0; l < 4; l++) {
        const float* b = (const float*)d_in[5 + 4 * l];
        float* xout = (l == 3) ? (float*)d_out : ((l & 1) ? bufB : bufA);
        const __half* awf = (l < 3) ? (waf + (size_t)l * 2048) : (const __half*)nullptr;

        layer_kernel<<<(N + NPB - 1) / NPB, 512, 0, stream>>>(xcur, acur, rowptr, deg, col,
                                                              w16f + (size_t)l * bf_halves_per_layer,
                                                              b, xout, awf, anext, N);
        xcur = xout;
        float* tmp = acur; acur = anext; anext = tmp;
    }
}